// Round 1
// baseline (587.833 us; speedup 1.0000x reference)
//
#include <hip/hip_runtime.h>

#define EPS 1e-6f

constexpr int Bn = 4096;   // batch rows
constexpr int Dn = 1024;   // feature dim
constexpr int Kn = 4096;   // codebook entries (64x64 grid)
constexpr int KB = 32;     // k-blocks = Kn / 128

// ---- c[k] = sum_d w[d][k]^2 - 2*eps*sum_d w[d][k] ------------------------
__global__ __launch_bounds__(256) void som_colstats(const float* __restrict__ w,
                                                    float* __restrict__ c) {
    __shared__ float sm2[4][64];
    __shared__ float sm1[4][64];
    const int tx = threadIdx.x & 63;
    const int ty = threadIdx.x >> 6;
    const int col = blockIdx.x * 64 + tx;
    float s2 = 0.f, s1 = 0.f;
    for (int d = ty; d < Dn; d += 4) {
        float v = w[d * Kn + col];
        s2 = fmaf(v, v, s2);
        s1 += v;
    }
    sm2[ty][tx] = s2; sm1[ty][tx] = s1;
    __syncthreads();
    if (ty == 0) {
        #pragma unroll
        for (int j = 1; j < 4; ++j) { s2 += sm2[j][tx]; s1 += sm1[j][tx]; }
        c[col] = s2 - 2.f * EPS * s1;
    }
}

// ---- main GEMM + fused per-row min/argmin over the 128-col tile ----------
// s[b][k] = c[k] - 2 * sum_d x[b][d]*w[d][k]   (d2 minus row-constant terms)
__global__ __launch_bounds__(256) void som_gemm_min(
    const float* __restrict__ x, const float* __restrict__ w,
    const float* __restrict__ c, float* __restrict__ pval,
    int* __restrict__ pidx) {
    __shared__ __align__(16) float As[16][128];   // [d][row]
    __shared__ __align__(16) float Bs[16][128];   // [d][col]
    const int tid = threadIdx.x;
    const int tx = tid & 15;          // column group (8 cols each)
    const int ty = tid >> 4;          // row group (8 rows each)
    const int rowBase = blockIdx.y * 128;
    const int colBase = blockIdx.x * 128;

    float acc[8][8];
    #pragma unroll
    for (int i = 0; i < 8; ++i)
        #pragma unroll
        for (int j = 0; j < 8; ++j) acc[i][j] = 0.f;

    for (int d0 = 0; d0 < Dn; d0 += 16) {
        // A tile: 128 rows x 16 d  (512 float4 loads, 2 per thread)
        #pragma unroll
        for (int i = 0; i < 2; ++i) {
            int f = tid + i * 256;
            int row = f >> 2;
            int dq = f & 3;
            float4 v = *(const float4*)(x + (size_t)(rowBase + row) * Dn + d0 + dq * 4);
            As[dq * 4 + 0][row] = v.x;
            As[dq * 4 + 1][row] = v.y;
            As[dq * 4 + 2][row] = v.z;
            As[dq * 4 + 3][row] = v.w;
        }
        // B tile: 16 d x 128 cols (contiguous rows, float4 straight through)
        #pragma unroll
        for (int i = 0; i < 2; ++i) {
            int f = tid + i * 256;
            int d = f >> 5;
            int kq = f & 31;
            float4 v = *(const float4*)(w + (size_t)(d0 + d) * Kn + colBase + kq * 4);
            *(float4*)&Bs[d][kq * 4] = v;
        }
        __syncthreads();
        #pragma unroll
        for (int dd = 0; dd < 16; ++dd) {
            float a[8], b[8];
            *(float4*)&a[0] = *(const float4*)&As[dd][ty * 8];
            *(float4*)&a[4] = *(const float4*)&As[dd][ty * 8 + 4];
            *(float4*)&b[0] = *(const float4*)&Bs[dd][tx * 8];
            *(float4*)&b[4] = *(const float4*)&Bs[dd][tx * 8 + 4];
            #pragma unroll
            for (int i = 0; i < 8; ++i)
                #pragma unroll
                for (int j = 0; j < 8; ++j)
                    acc[i][j] = fmaf(a[i], b[j], acc[i][j]);
        }
        __syncthreads();
    }

    // epilogue: per-row min/argmin of s = c[k] - 2*xw (first-occurrence ties)
    float cv[8];
    #pragma unroll
    for (int j = 0; j < 8; ++j) cv[j] = c[colBase + tx * 8 + j];
    #pragma unroll
    for (int i = 0; i < 8; ++i) {
        float best = 3.4e38f;
        int bidx = 0x7FFFFFFF;
        #pragma unroll
        for (int j = 0; j < 8; ++j) {
            float s = fmaf(-2.f, acc[i][j], cv[j]);
            int k = colBase + tx * 8 + j;
            if (s < best) { best = s; bidx = k; }   // strict < keeps lowest k
        }
        // reduce across the 16 column-threads (lanes grouped by low 4 bits)
        #pragma unroll
        for (int off = 1; off < 16; off <<= 1) {
            float ov = __shfl_xor(best, off);
            int   oi = __shfl_xor(bidx, off);
            if (ov < best || (ov == best && oi < bidx)) { best = ov; bidx = oi; }
        }
        if (tx == 0) {
            int row = rowBase + ty * 8 + i;
            pval[row * KB + blockIdx.x] = best;
            pidx[row * KB + blockIdx.x] = bidx;
        }
    }
}

// ---- finalize: one wave per row ------------------------------------------
__global__ __launch_bounds__(256) void som_finalize(
    const float* __restrict__ x, const float* __restrict__ loc,
    const float* __restrict__ pval, const int* __restrict__ pidx,
    float* __restrict__ out) {
    const int wave = threadIdx.x >> 6;
    const int lane = threadIdx.x & 63;
    const int row = blockIdx.x * 4 + wave;
    const float4* xr = (const float4*)(x + (size_t)row * Dn);
    float s2 = 0.f, s1 = 0.f;
    #pragma unroll
    for (int j = 0; j < 4; ++j) {
        float4 v = xr[lane + 64 * j];
        s2 += v.x * v.x + v.y * v.y + v.z * v.z + v.w * v.w;
        s1 += v.x + v.y + v.z + v.w;
    }
    float best = 3.4e38f;
    int bidx = 0x7FFFFFFF;
    if (lane < KB) { best = pval[row * KB + lane]; bidx = pidx[row * KB + lane]; }
    #pragma unroll
    for (int off = 32; off >= 1; off >>= 1) {
        s2 += __shfl_xor(s2, off);
        s1 += __shfl_xor(s1, off);
        float ov = __shfl_xor(best, off);
        int   oi = __shfl_xor(bidx, off);
        if (ov < best || (ov == best && oi < bidx)) { best = ov; bidx = oi; }
    }
    if (lane == 0) {
        float r = s2 + 2.f * EPS * s1 + (float)Dn * EPS * EPS;
        float d2 = fmaxf(r + best, 0.f);
        float dist = sqrtf(d2);
        out[2 * row]     = loc[2 * bidx];
        out[2 * row + 1] = loc[2 * bidx + 1];
        out[8193 + row]  = (float)bidx;   // indexes chunk starts after 8192+1
        atomicAdd(&out[8192], dist * (1.0f / (float)Bn));
    }
}

extern "C" void kernel_launch(void* const* d_in, const int* in_sizes, int n_in,
                              void* d_out, int out_size, void* d_ws, size_t ws_size,
                              hipStream_t stream) {
    const float* x   = (const float*)d_in[0];   // [B, D]
    const float* w   = (const float*)d_in[1];   // [D, K]
    const float* loc = (const float*)d_in[2];   // [K, 2]
    float* out = (float*)d_out;

    float* c    = (float*)d_ws;                 // K floats
    float* pval = c + Kn;                       // B*KB floats
    int*   pidx = (int*)(pval + (size_t)Bn * KB);

    // loss accumulator must be zeroed every call (harness poisons d_out)
    hipMemsetAsync((char*)d_out + 8192 * sizeof(float), 0, sizeof(float), stream);
    som_colstats<<<Kn / 64, 256, 0, stream>>>(w, c);
    som_gemm_min<<<dim3(Kn / 128, Bn / 128), 256, 0, stream>>>(x, w, c, pval, pidx);
    som_finalize<<<Bn / 4, 256, 0, stream>>>(x, loc, pval, pidx, out);
}

// Round 2
// 429.042 us; speedup vs baseline: 1.3701x; 1.3701x over previous
//
#include <hip/hip_runtime.h>

#define EPS 1e-6f

constexpr int Bn = 4096;   // batch rows
constexpr int Dn = 1024;   // feature dim
constexpr int Kn = 4096;   // codebook entries

typedef __attribute__((ext_vector_type(8))) short short8;   // 8 bf16 (4 VGPRs)
typedef __attribute__((ext_vector_type(4))) float f32x4;    // MFMA accumulator

__device__ inline short f2bf(float f) {            // fp32 -> bf16, RNE
    unsigned u = __float_as_uint(f);
    unsigned r = (u + 0x7FFFu + ((u >> 16) & 1u)) >> 16;
    return (short)r;
}

#define GLD_LDS16(gp, lp) __builtin_amdgcn_global_load_lds(                  \
    (const __attribute__((address_space(1))) void*)(gp),                     \
    (__attribute__((address_space(3))) void*)(lp), 16, 0, 0)

// ---- x fp32 -> bf16 -------------------------------------------------------
__global__ __launch_bounds__(256) void som_convert_x(const float* __restrict__ x,
                                                     short* __restrict__ xb) {
    size_t i = (size_t)blockIdx.x * 256 + threadIdx.x;   // 8 elems / thread
    const float4* p = (const float4*)x;
    float4 a = p[i * 2], b = p[i * 2 + 1];
    short8 o;
    o[0] = f2bf(a.x); o[1] = f2bf(a.y); o[2] = f2bf(a.z); o[3] = f2bf(a.w);
    o[4] = f2bf(b.x); o[5] = f2bf(b.y); o[6] = f2bf(b.z); o[7] = f2bf(b.w);
    *(short8*)(xb + i * 8) = o;
}

// ---- w [D][K] -> wt [K][D] bf16 + wtf [K][D] fp32 (for exact rescore) -----
__global__ __launch_bounds__(256) void som_transpose(const float* __restrict__ w,
                                                     float* __restrict__ wtf,
                                                     short* __restrict__ wt) {
    __shared__ float t[32][33];
    const int k0 = blockIdx.x * 32, d0 = blockIdx.y * 32;
    const int tx = threadIdx.x & 31, ty = threadIdx.x >> 5;
    #pragma unroll
    for (int i = 0; i < 4; ++i)
        t[ty + i * 8][tx] = w[(size_t)(d0 + ty + i * 8) * Kn + k0 + tx];
    __syncthreads();
    #pragma unroll
    for (int i = 0; i < 4; ++i) {
        int kr = ty + i * 8;
        float v = t[tx][kr];
        wtf[(size_t)(k0 + kr) * Dn + d0 + tx] = v;
        wt [(size_t)(k0 + kr) * Dn + d0 + tx] = f2bf(v);
    }
}

// ---- c[k] = sum_d w^2 - 2*eps*sum_d w  (reads original w, coalesced) ------
__global__ __launch_bounds__(256) void som_colstats(const float* __restrict__ w,
                                                    float* __restrict__ c) {
    __shared__ float sm2[4][64];
    __shared__ float sm1[4][64];
    const int tx = threadIdx.x & 63;
    const int ty = threadIdx.x >> 6;
    const int col = blockIdx.x * 64 + tx;
    float s2 = 0.f, s1 = 0.f;
    for (int d = ty; d < Dn; d += 4) {
        float v = w[(size_t)d * Kn + col];
        s2 = fmaf(v, v, s2);
        s1 += v;
    }
    sm2[ty][tx] = s2; sm1[ty][tx] = s1;
    __syncthreads();
    if (ty == 0) {
        #pragma unroll
        for (int j = 1; j < 4; ++j) { s2 += sm2[j][tx]; s1 += sm1[j][tx]; }
        c[col] = s2 - 2.f * EPS * s1;
    }
}

// ---- bf16 MFMA GEMM, fused per-row top-2 over each 64-col group -----------
// s[b][k] = c[k] - 2 * dot_bf16(xb[b], wt[k]); exact argmin recovered later.
__global__ __launch_bounds__(256) void som_gemm_bf16(
    const short* __restrict__ xb, const short* __restrict__ wt,
    const float* __restrict__ c, float* __restrict__ pval,
    int* __restrict__ pidx) {
    __shared__ short As[128 * 64];   // [row][d], d-segments XOR-swizzled
    __shared__ short Bs[128 * 64];   // [col][d], same swizzle
    const int tid = threadIdx.x;
    const int lane = tid & 63;
    const int wid = tid >> 6;
    const int wm = wid >> 1, wn = wid & 1;    // 2x2 waves of 64x64
    const int rowBase = blockIdx.y * 128, colBase = blockIdx.x * 128;

    f32x4 acc[4][4] = {};

    for (int d0 = 0; d0 < Dn; d0 += 64) {
        // stage 128x64 bf16 tiles; global seg permuted by s^(r&7) so the
        // wave-uniform-base LDS placement yields a conflict-free read layout
        #pragma unroll
        for (int i = 0; i < 4; ++i) {
            int chunk = i * 256 + wid * 64 + lane;     // 16B chunk id
            int r = chunk >> 3, s = chunk & 7;
            int sg = ((s ^ (r & 7)) << 3);             // swizzled d-offset (elems)
            GLD_LDS16(xb + (size_t)(rowBase + r) * Dn + d0 + sg,
                      &As[(i * 256 + wid * 64) * 8]);
            GLD_LDS16(wt + (size_t)(colBase + r) * Dn + d0 + sg,
                      &Bs[(i * 256 + wid * 64) * 8]);
        }
        __syncthreads();
        const int mr = wm * 64 + (lane & 15);
        const int nr = wn * 64 + (lane & 15);
        const int q = lane >> 4;
        #pragma unroll
        for (int kk = 0; kk < 2; ++kk) {
            short8 a[4], b[4];
            #pragma unroll
            for (int i = 0; i < 4; ++i) {
                int r = mr + i * 16;
                int sa = (kk * 4 + q) ^ (r & 7);
                a[i] = *(const short8*)&As[r * 64 + sa * 8];
                int r2 = nr + i * 16;
                int sb = (kk * 4 + q) ^ (r2 & 7);
                b[i] = *(const short8*)&Bs[r2 * 64 + sb * 8];
            }
            #pragma unroll
            for (int i = 0; i < 4; ++i)
                #pragma unroll
                for (int j = 0; j < 4; ++j)
                    acc[i][j] = __builtin_amdgcn_mfma_f32_16x16x32_bf16(
                        a[i], b[j], acc[i][j], 0, 0, 0);
        }
        __syncthreads();
    }

    // epilogue: per (row, this wave's 64 cols) keep top-2 (val, idx)
    const int cn = lane & 15, q = lane >> 4;
    const int nbase = colBase + wn * 64;
    float cv[4];
    #pragma unroll
    for (int j = 0; j < 4; ++j) cv[j] = c[nbase + j * 16 + cn];
    #pragma unroll
    for (int i = 0; i < 4; ++i) {
        #pragma unroll
        for (int rg = 0; rg < 4; ++rg) {
            float v1 = 3.4e38f, v2 = 3.4e38f;
            int i1 = 0x7fffffff, i2 = 0x7fffffff;
            auto upd = [&](float s, int k) {
                if (s < v1 || (s == v1 && k < i1)) { v2 = v1; i2 = i1; v1 = s; i1 = k; }
                else if (s < v2 || (s == v2 && k < i2)) { v2 = s; i2 = k; }
            };
            #pragma unroll
            for (int j = 0; j < 4; ++j)
                upd(fmaf(-2.f, acc[i][j][rg], cv[j]), nbase + j * 16 + cn);
            #pragma unroll
            for (int off = 1; off < 16; off <<= 1) {
                float ov1 = __shfl_xor(v1, off); int oi1 = __shfl_xor(i1, off);
                float ov2 = __shfl_xor(v2, off); int oi2 = __shfl_xor(i2, off);
                upd(ov1, oi1);
                upd(ov2, oi2);
            }
            if (cn == 0) {
                int mrow = rowBase + wm * 64 + i * 16 + q * 4 + rg;
                size_t e = (size_t)mrow * 128 + blockIdx.x * 4 + wn * 2;
                pval[e] = v1; pidx[e] = i1;
                pval[e + 1] = v2; pidx[e + 1] = i2;
            }
        }
    }
}

// ---- finalize: per row, exact fp32 rescore of all candidates in margin ----
__global__ __launch_bounds__(256) void som_finalize(
    const float* __restrict__ x, const float* __restrict__ wtf,
    const float* __restrict__ c, const float* __restrict__ loc,
    const float* __restrict__ pval, const int* __restrict__ pidx,
    float* __restrict__ out) {
    const int lane = threadIdx.x & 63;
    const int row = blockIdx.x * 4 + (threadIdx.x >> 6);

    const float4* xr = (const float4*)(x + (size_t)row * Dn);
    float4 xv[4];
    float s2 = 0.f, s1 = 0.f;
    #pragma unroll
    for (int j = 0; j < 4; ++j) {
        xv[j] = xr[lane * 4 + j];
        s2 += xv[j].x * xv[j].x + xv[j].y * xv[j].y + xv[j].z * xv[j].z + xv[j].w * xv[j].w;
        s1 += xv[j].x + xv[j].y + xv[j].z + xv[j].w;
    }
    #pragma unroll
    for (int off = 1; off < 64; off <<= 1) {
        s2 += __shfl_xor(s2, off);
        s1 += __shfl_xor(s1, off);
    }
    const float rrow = s2 + 2.f * EPS * s1 + (float)Dn * EPS * EPS;

    float v0 = pval[(size_t)row * 128 + lane];
    float v1 = pval[(size_t)row * 128 + 64 + lane];
    int   k0 = pidx[(size_t)row * 128 + lane];
    int   k1 = pidx[(size_t)row * 128 + 64 + lane];
    float g = fminf(v0, v1);
    #pragma unroll
    for (int off = 1; off < 64; off <<= 1) g = fminf(g, __shfl_xor(g, off));
    const float thr = g + 4.0f;   // 26 sigma of bf16 dot noise
    unsigned long long m0 = __ballot(v0 <= thr);
    unsigned long long m1 = __ballot(v1 <= thr);

    float bestd2 = 3.4e38f; int bestk = 0x7fffffff;
    #pragma unroll
    for (int slot = 0; slot < 2; ++slot) {
        unsigned long long m = slot ? m1 : m0;
        while (m) {
            int src = __builtin_ctzll(m); m &= m - 1;
            int k = __shfl(slot ? k1 : k0, src);
            const float4* wr = (const float4*)(wtf + (size_t)k * Dn);
            float dt = 0.f;
            #pragma unroll
            for (int j = 0; j < 4; ++j) {
                float4 wv = wr[lane * 4 + j];
                dt += xv[j].x * wv.x + xv[j].y * wv.y + xv[j].z * wv.z + xv[j].w * wv.w;
            }
            #pragma unroll
            for (int off = 1; off < 64; off <<= 1) dt += __shfl_xor(dt, off);
            float d2 = rrow + c[k] - 2.f * dt;
            if (d2 < bestd2 || (d2 == bestd2 && k < bestk)) { bestd2 = d2; bestk = k; }
        }
    }
    if (lane == 0) {
        float dist = sqrtf(fmaxf(bestd2, 0.f));
        out[2 * row]     = loc[2 * bestk];
        out[2 * row + 1] = loc[2 * bestk + 1];
        out[8193 + row]  = (float)bestk;
        atomicAdd(&out[8192], dist * (1.0f / (float)Bn));
    }
}

extern "C" void kernel_launch(void* const* d_in, const int* in_sizes, int n_in,
                              void* d_out, int out_size, void* d_ws, size_t ws_size,
                              hipStream_t stream) {
    const float* x   = (const float*)d_in[0];   // [B, D]
    const float* w   = (const float*)d_in[1];   // [D, K]
    const float* loc = (const float*)d_in[2];   // [K, 2]
    float* out = (float*)d_out;

    float* c    = (float*)d_ws;                          // 16 KB
    float* wtf  = c + Kn;                                // 16 MB  [K][D] fp32
    short* wt   = (short*)(wtf + (size_t)Kn * Dn);       // 8 MB   [K][D] bf16
    short* xb   = wt + (size_t)Kn * Dn;                  // 8 MB   [B][D] bf16
    float* pval = (float*)(xb + (size_t)Bn * Dn);        // 2 MB
    int*   pidx = (int*)(pval + (size_t)Bn * 128);       // 2 MB

    // loss accumulator must be zeroed every call (harness poisons d_out)
    hipMemsetAsync((char*)d_out + 8192 * sizeof(float), 0, sizeof(float), stream);
    som_convert_x<<<(Bn * Dn) / (8 * 256), 256, 0, stream>>>(x, xb);
    som_transpose<<<dim3(Kn / 32, Dn / 32), 256, 0, stream>>>(w, wtf, wt);
    som_colstats<<<Kn / 64, 256, 0, stream>>>(w, c);
    som_gemm_bf16<<<dim3(Kn / 128, Bn / 128), 256, 0, stream>>>(xb, wt, c, pval, pidx);
    som_finalize<<<Bn / 4, 256, 0, stream>>>(x, wtf, c, loc, pval, pidx, out);
}

// Round 3
// 262.030 us; speedup vs baseline: 2.2434x; 1.6374x over previous
//
#include <hip/hip_runtime.h>

#define EPS 1e-6f

constexpr int Bn = 4096;   // batch rows
constexpr int Dn = 1024;   // feature dim
constexpr int Kn = 4096;   // codebook entries

typedef __attribute__((ext_vector_type(8))) short short8;   // 8 bf16 (4 VGPRs)
typedef __attribute__((ext_vector_type(4))) float f32x4;    // MFMA accumulator

__device__ inline short f2bf(float f) {            // fp32 -> bf16, RNE
    unsigned u = __float_as_uint(f);
    unsigned r = (u + 0x7FFFu + ((u >> 16) & 1u)) >> 16;
    return (short)r;
}

// pack candidate k (12 bits) into low mantissa of positive score s.
// Monotone in s (|error| <= ~0.25 at s~1000), ties break to smaller k.
__device__ inline float packcand(float s, int k) {
    unsigned b = __float_as_uint(fmaxf(s, 0.5f));
    return __uint_as_float((b & 0xFFFFF000u) | (unsigned)k);
}

#define GLD_LDS16(gp, lp) __builtin_amdgcn_global_load_lds(                  \
    (const __attribute__((address_space(1))) void*)(gp),                     \
    (__attribute__((address_space(3))) void*)(lp), 16, 0, 0)

// ---- x fp32 -> bf16 -------------------------------------------------------
__global__ __launch_bounds__(256) void som_convert_x(const float* __restrict__ x,
                                                     short* __restrict__ xb) {
    size_t i = (size_t)blockIdx.x * 256 + threadIdx.x;   // 8 elems / thread
    const float4* p = (const float4*)x;
    float4 a = p[i * 2], b = p[i * 2 + 1];
    short8 o;
    o[0] = f2bf(a.x); o[1] = f2bf(a.y); o[2] = f2bf(a.z); o[3] = f2bf(a.w);
    o[4] = f2bf(b.x); o[5] = f2bf(b.y); o[6] = f2bf(b.z); o[7] = f2bf(b.w);
    *(short8*)(xb + i * 8) = o;
}

// ---- w [D][K] -> wt [K][D] bf16 + wtf [K][D] fp32 (for exact rescore) -----
__global__ __launch_bounds__(256) void som_transpose(const float* __restrict__ w,
                                                     float* __restrict__ wtf,
                                                     short* __restrict__ wt) {
    __shared__ float t[32][33];
    const int k0 = blockIdx.x * 32, d0 = blockIdx.y * 32;
    const int tx = threadIdx.x & 31, ty = threadIdx.x >> 5;
    #pragma unroll
    for (int i = 0; i < 4; ++i)
        t[ty + i * 8][tx] = w[(size_t)(d0 + ty + i * 8) * Kn + k0 + tx];
    __syncthreads();
    #pragma unroll
    for (int i = 0; i < 4; ++i) {
        int kr = ty + i * 8;
        float v = t[tx][kr];
        wtf[(size_t)(k0 + kr) * Dn + d0 + tx] = v;
        wt [(size_t)(k0 + kr) * Dn + d0 + tx] = f2bf(v);
    }
}

// ---- c[k] = sum_d w^2 - 2*eps*sum_d w; also zero the loss accumulator -----
__global__ __launch_bounds__(256) void som_colstats(const float* __restrict__ w,
                                                    float* __restrict__ c,
                                                    float* __restrict__ out) {
    if (blockIdx.x == 0 && threadIdx.x == 0) out[8192] = 0.f;
    __shared__ float sm2[4][64];
    __shared__ float sm1[4][64];
    const int tx = threadIdx.x & 63;
    const int ty = threadIdx.x >> 6;
    const int col = blockIdx.x * 64 + tx;
    float s2 = 0.f, s1 = 0.f;
    for (int d = ty; d < Dn; d += 4) {
        float v = w[(size_t)d * Kn + col];
        s2 = fmaf(v, v, s2);
        s1 += v;
    }
    sm2[ty][tx] = s2; sm1[ty][tx] = s1;
    __syncthreads();
    if (ty == 0) {
        #pragma unroll
        for (int j = 1; j < 4; ++j) { s2 += sm2[j][tx]; s1 += sm1[j][tx]; }
        c[col] = s2 - 2.f * EPS * s1;
    }
}

// ---- bf16 MFMA GEMM, fused per-row packed top-2 per 64-col group ----------
// s[b][k] = c[k] - 2 * dot_bf16(xb[b], wt[k]); exact argmin recovered later.
__global__ __launch_bounds__(256) void som_gemm_bf16(
    const short* __restrict__ xb, const short* __restrict__ wt,
    const float* __restrict__ c, float* __restrict__ pval) {
    __shared__ short As[128 * 64];   // [row][d] row-major (m97 layout)
    __shared__ short Bs[128 * 64];   // [col][d]
    const int tid = threadIdx.x;
    const int lane = tid & 63;
    const int wid = tid >> 6;
    const int wm = wid >> 1, wn = wid & 1;    // 2x2 waves of 64x64
    const int rowBase = blockIdx.y * 128, colBase = blockIdx.x * 128;

    f32x4 acc[4][4] = {};

    for (int d0 = 0; d0 < Dn; d0 += 64) {
        // linear staging: per-wave global addresses ascending-contiguous
        // (8 rows x 128 B per issue); LDS dst = wave-uniform base + lane*16
        #pragma unroll
        for (int i = 0; i < 4; ++i) {
            int chunk = i * 256 + tid;
            int r = chunk >> 3, s = chunk & 7;
            GLD_LDS16(xb + (size_t)(rowBase + r) * Dn + d0 + s * 8,
                      &As[(i * 256 + wid * 64) * 8]);
            GLD_LDS16(wt + (size_t)(colBase + r) * Dn + d0 + s * 8,
                      &Bs[(i * 256 + wid * 64) * 8]);
        }
        __syncthreads();
        const int mr = wm * 64 + (lane & 15);
        const int nr = wn * 64 + (lane & 15);
        const int q = lane >> 4;
        #pragma unroll
        for (int kk = 0; kk < 2; ++kk) {
            short8 a[4], b[4];
            #pragma unroll
            for (int i = 0; i < 4; ++i) {
                a[i] = *(const short8*)&As[(mr + i * 16) * 64 + (kk * 4 + q) * 8];
                b[i] = *(const short8*)&Bs[(nr + i * 16) * 64 + (kk * 4 + q) * 8];
            }
            #pragma unroll
            for (int i = 0; i < 4; ++i)
                #pragma unroll
                for (int j = 0; j < 4; ++j)
                    acc[i][j] = __builtin_amdgcn_mfma_f32_16x16x32_bf16(
                        a[i], b[j], acc[i][j], 0, 0, 0);
        }
        __syncthreads();
    }

    // epilogue: per (row, this wave's 64 cols) packed top-2
    const int cn = lane & 15, q = lane >> 4;
    const int nbase = colBase + wn * 64;
    float cv[4];
    #pragma unroll
    for (int j = 0; j < 4; ++j) cv[j] = c[nbase + j * 16 + cn];
    #pragma unroll
    for (int i = 0; i < 4; ++i) {
        #pragma unroll
        for (int rg = 0; rg < 4; ++rg) {     // handles rows q*4+rg for all q
            float p1 = 3.4e38f, p2 = 3.4e38f;
            #pragma unroll
            for (int j = 0; j < 4; ++j) {
                float p = packcand(fmaf(-2.f, acc[i][j][rg], cv[j]),
                                   nbase + j * 16 + cn);
                float lo = fminf(p1, p), hi = fmaxf(p1, p);
                p1 = lo; p2 = fminf(p2, hi);
            }
            #pragma unroll
            for (int off = 1; off < 16; off <<= 1) {
                float o1 = __shfl_xor(p1, off);
                float o2 = __shfl_xor(p2, off);
                float lo = fminf(p1, o1), hi = fmaxf(p1, o1);
                p1 = lo; p2 = fminf(hi, fminf(p2, o2));
            }
            if (cn == 0) {
                int mrow = rowBase + wm * 64 + i * 16 + q * 4 + rg;
                size_t e = (size_t)mrow * 128 + blockIdx.x * 4 + wn * 2;
                pval[e] = p1; pval[e + 1] = p2;
            }
        }
    }
}

// ---- finalize: per row, exact fp32 rescore of all candidates in margin ----
__global__ __launch_bounds__(256) void som_finalize(
    const float* __restrict__ x, const float* __restrict__ wtf,
    const float* __restrict__ c, const float* __restrict__ loc,
    const float* __restrict__ pval, float* __restrict__ out) {
    const int lane = threadIdx.x & 63;
    const int row = blockIdx.x * 4 + (threadIdx.x >> 6);

    const float4* xr = (const float4*)(x + (size_t)row * Dn);
    float4 xv[4];
    float s2 = 0.f, s1 = 0.f;
    #pragma unroll
    for (int j = 0; j < 4; ++j) {
        xv[j] = xr[lane * 4 + j];
        s2 += xv[j].x * xv[j].x + xv[j].y * xv[j].y + xv[j].z * xv[j].z + xv[j].w * xv[j].w;
        s1 += xv[j].x + xv[j].y + xv[j].z + xv[j].w;
    }
    #pragma unroll
    for (int off = 1; off < 64; off <<= 1) {
        s2 += __shfl_xor(s2, off);
        s1 += __shfl_xor(s1, off);
    }
    const float rrow = s2 + 2.f * EPS * s1 + (float)Dn * EPS * EPS;

    float v0 = pval[(size_t)row * 128 + lane];
    float v1 = pval[(size_t)row * 128 + 64 + lane];
    float g = fminf(v0, v1);
    #pragma unroll
    for (int off = 1; off < 64; off <<= 1) g = fminf(g, __shfl_xor(g, off));
    const float thr = g + 6.0f;   // bf16 noise (15 sigma) + packing error
    unsigned long long m0 = __ballot(v0 <= thr);
    unsigned long long m1 = __ballot(v1 <= thr);

    float bestd2 = 3.4e38f; int bestk = 0x7fffffff;
    #pragma unroll
    for (int slot = 0; slot < 2; ++slot) {
        unsigned long long m = slot ? m1 : m0;
        float vs = slot ? v1 : v0;
        while (m) {
            int src = __builtin_ctzll(m); m &= m - 1;
            int k = ((int)__float_as_uint(__shfl(vs, src))) & 0xFFF;
            const float4* wr = (const float4*)(wtf + (size_t)k * Dn);
            float dt = 0.f;
            #pragma unroll
            for (int j = 0; j < 4; ++j) {
                float4 wv = wr[lane * 4 + j];
                dt += xv[j].x * wv.x + xv[j].y * wv.y + xv[j].z * wv.z + xv[j].w * wv.w;
            }
            #pragma unroll
            for (int off = 1; off < 64; off <<= 1) dt += __shfl_xor(dt, off);
            float d2 = rrow + c[k] - 2.f * dt;
            if (d2 < bestd2 || (d2 == bestd2 && k < bestk)) { bestd2 = d2; bestk = k; }
        }
    }
    if (lane == 0) {
        float dist = sqrtf(fmaxf(bestd2, 0.f));
        out[2 * row]     = loc[2 * bestk];
        out[2 * row + 1] = loc[2 * bestk + 1];
        out[8193 + row]  = (float)bestk;
        atomicAdd(&out[8192], dist * (1.0f / (float)Bn));
    }
}

extern "C" void kernel_launch(void* const* d_in, const int* in_sizes, int n_in,
                              void* d_out, int out_size, void* d_ws, size_t ws_size,
                              hipStream_t stream) {
    const float* x   = (const float*)d_in[0];   // [B, D]
    const float* w   = (const float*)d_in[1];   // [D, K]
    const float* loc = (const float*)d_in[2];   // [K, 2]
    float* out = (float*)d_out;

    float* c    = (float*)d_ws;                          // 16 KB
    float* wtf  = c + Kn;                                // 16 MB  [K][D] fp32
    short* wt   = (short*)(wtf + (size_t)Kn * Dn);       // 8 MB   [K][D] bf16
    short* xb   = wt + (size_t)Kn * Dn;                  // 8 MB   [B][D] bf16
    float* pval = (float*)(xb + (size_t)Bn * Dn);        // 2 MB packed top-2

    som_convert_x<<<(Bn * Dn) / (8 * 256), 256, 0, stream>>>(x, xb);
    som_transpose<<<dim3(Kn / 32, Dn / 32), 256, 0, stream>>>(w, wtf, wt);
    som_colstats<<<Kn / 64, 256, 0, stream>>>(w, c, out);
    som_gemm_bf16<<<dim3(Kn / 128, Bn / 128), 256, 0, stream>>>(xb, wt, c, pval);
    som_finalize<<<Bn / 4, 256, 0, stream>>>(x, wtf, c, loc, pval, out);
}

// Round 4
// 204.054 us; speedup vs baseline: 2.8808x; 1.2841x over previous
//
#include <hip/hip_runtime.h>

#define EPS 1e-6f

constexpr int Bn = 4096;   // batch rows
constexpr int Dn = 1024;   // feature dim
constexpr int Kn = 4096;   // codebook entries

typedef __attribute__((ext_vector_type(8))) short short8;   // 8 bf16 (4 VGPRs)
typedef __attribute__((ext_vector_type(4))) float f32x4;    // MFMA accumulator

__device__ inline short f2bf(float f) {            // fp32 -> bf16, RNE
    unsigned u = __float_as_uint(f);
    unsigned r = (u + 0x7FFFu + ((u >> 16) & 1u)) >> 16;
    return (short)r;
}

// pack candidate k (12 bits) into low mantissa of positive score s.
// Monotone in s (|error| <= ~0.25 at s~1000), ties break to smaller k.
__device__ inline float packcand(float s, int k) {
    unsigned b = __float_as_uint(fmaxf(s, 0.5f));
    return __uint_as_float((b & 0xFFFFF000u) | (unsigned)k);
}

#define GLD_LDS16(gp, lp) __builtin_amdgcn_global_load_lds(                  \
    (const __attribute__((address_space(1))) void*)(gp),                     \
    (__attribute__((address_space(3))) void*)(lp), 16, 0, 0)

// ---- x fp32 -> bf16 (also zeroes the loss accumulator) --------------------
__global__ __launch_bounds__(256) void som_convert_x(const float* __restrict__ x,
                                                     short* __restrict__ xb,
                                                     float* __restrict__ out) {
    if (blockIdx.x == 0 && threadIdx.x == 0) out[8192] = 0.f;
    size_t i = (size_t)blockIdx.x * 256 + threadIdx.x;   // 8 elems / thread
    const float4* p = (const float4*)x;
    float4 a = p[i * 2], b = p[i * 2 + 1];
    short8 o;
    o[0] = f2bf(a.x); o[1] = f2bf(a.y); o[2] = f2bf(a.z); o[3] = f2bf(a.w);
    o[4] = f2bf(b.x); o[5] = f2bf(b.y); o[6] = f2bf(b.z); o[7] = f2bf(b.w);
    *(short8*)(xb + i * 8) = o;
}

// ---- w [D][K] -> wt [K][D] bf16 + wtf [K][D] fp32; 64x64 tiles ------------
__global__ __launch_bounds__(256) void som_transpose(const float* __restrict__ w,
                                                     float* __restrict__ wtf,
                                                     short* __restrict__ wt) {
    __shared__ float t[64][65];
    const int k0 = blockIdx.x * 64, d0 = blockIdx.y * 64;
    const int tx = threadIdx.x & 63, ty = threadIdx.x >> 6;
    #pragma unroll
    for (int i = 0; i < 16; ++i) {
        int d = i * 4 + ty;
        t[d][tx] = w[(size_t)(d0 + d) * Kn + k0 + tx];   // 256 B coalesced
    }
    __syncthreads();
    #pragma unroll
    for (int i = 0; i < 16; ++i) {
        int kr = i * 4 + ty;
        float v = t[tx][kr];                              // stride 65: no conflicts
        wtf[(size_t)(k0 + kr) * Dn + d0 + tx] = v;        // 256 B coalesced
        wt [(size_t)(k0 + kr) * Dn + d0 + tx] = f2bf(v);
    }
}

// ---- c[k] from wtf rows (coalesced); one wave per k -----------------------
__global__ __launch_bounds__(256) void som_colstats(const float* __restrict__ wtf,
                                                    float* __restrict__ c) {
    const int lane = threadIdx.x & 63;
    const int k = blockIdx.x * 4 + (threadIdx.x >> 6);
    const float4* wr = (const float4*)(wtf + (size_t)k * Dn);
    float s2 = 0.f, s1 = 0.f;
    #pragma unroll
    for (int j = 0; j < 4; ++j) {
        float4 v = wr[lane * 4 + j];
        s2 += v.x * v.x + v.y * v.y + v.z * v.z + v.w * v.w;
        s1 += v.x + v.y + v.z + v.w;
    }
    #pragma unroll
    for (int off = 1; off < 64; off <<= 1) {
        s2 += __shfl_xor(s2, off);
        s1 += __shfl_xor(s1, off);
    }
    if (lane == 0) c[k] = s2 - 2.f * EPS * s1;
}

// ---- bf16 MFMA GEMM, fused per-row packed top-2 per 64-col group ----------
// s[b][k] = c[k] - 2 * dot_bf16(xb[b], wt[k]); exact argmin recovered later.
// 1D grid of 1024 blocks, XCD-swizzled: xcd = f&7 owns row-blocks xcd*4..+3,
// so each XCD's 1 MB xb slab stays hot in its 4 MB L2 while wt streams.
__global__ __launch_bounds__(256) void som_gemm_bf16(
    const short* __restrict__ xb, const short* __restrict__ wt,
    const float* __restrict__ c, float* __restrict__ pval) {
    __shared__ short As[128 * 64];   // [row][d] row-major (m97 layout)
    __shared__ short Bs[128 * 64];   // [col][d]
    const int tid = threadIdx.x;
    const int lane = tid & 63;
    const int wid = tid >> 6;
    const int wm = wid >> 1, wn = wid & 1;    // 2x2 waves of 64x64
    const int f = blockIdx.x;
    const int xcd = f & 7;
    const int ib = f >> 3;                    // 0..127 within XCD
    const int rb = xcd * 4 + (ib & 3);        // row-block 0..31
    const int cb = ib >> 2;                   // col-block 0..31
    const int rowBase = rb * 128, colBase = cb * 128;

    f32x4 acc[4][4] = {};

    for (int d0 = 0; d0 < Dn; d0 += 64) {
        // linear staging: per-wave global addresses ascending-contiguous
        // (8 rows x 128 B per issue); LDS dst = wave-uniform base + lane*16
        #pragma unroll
        for (int i = 0; i < 4; ++i) {
            int chunk = i * 256 + tid;
            int r = chunk >> 3, s = chunk & 7;
            GLD_LDS16(xb + (size_t)(rowBase + r) * Dn + d0 + s * 8,
                      &As[(i * 256 + wid * 64) * 8]);
            GLD_LDS16(wt + (size_t)(colBase + r) * Dn + d0 + s * 8,
                      &Bs[(i * 256 + wid * 64) * 8]);
        }
        __syncthreads();
        const int mr = wm * 64 + (lane & 15);
        const int nr = wn * 64 + (lane & 15);
        const int q = lane >> 4;
        #pragma unroll
        for (int kk = 0; kk < 2; ++kk) {
            short8 a[4], b[4];
            #pragma unroll
            for (int i = 0; i < 4; ++i) {
                a[i] = *(const short8*)&As[(mr + i * 16) * 64 + (kk * 4 + q) * 8];
                b[i] = *(const short8*)&Bs[(nr + i * 16) * 64 + (kk * 4 + q) * 8];
            }
            #pragma unroll
            for (int i = 0; i < 4; ++i)
                #pragma unroll
                for (int j = 0; j < 4; ++j)
                    acc[i][j] = __builtin_amdgcn_mfma_f32_16x16x32_bf16(
                        a[i], b[j], acc[i][j], 0, 0, 0);
        }
        __syncthreads();
    }

    // epilogue: per (row, this wave's 64 cols) packed top-2
    const int cn = lane & 15, q = lane >> 4;
    const int nbase = colBase + wn * 64;
    float cv[4];
    #pragma unroll
    for (int j = 0; j < 4; ++j) cv[j] = c[nbase + j * 16 + cn];
    #pragma unroll
    for (int i = 0; i < 4; ++i) {
        #pragma unroll
        for (int rg = 0; rg < 4; ++rg) {     // handles rows q*4+rg for all q
            float p1 = 3.4e38f, p2 = 3.4e38f;
            #pragma unroll
            for (int j = 0; j < 4; ++j) {
                float p = packcand(fmaf(-2.f, acc[i][j][rg], cv[j]),
                                   nbase + j * 16 + cn);
                float lo = fminf(p1, p), hi = fmaxf(p1, p);
                p1 = lo; p2 = fminf(p2, hi);
            }
            #pragma unroll
            for (int off = 1; off < 16; off <<= 1) {
                float o1 = __shfl_xor(p1, off);
                float o2 = __shfl_xor(p2, off);
                float lo = fminf(p1, o1), hi = fmaxf(p1, o1);
                p1 = lo; p2 = fminf(hi, fminf(p2, o2));
            }
            if (cn == 0) {
                int mrow = rowBase + wm * 64 + i * 16 + q * 4 + rg;
                size_t e = (size_t)mrow * 128 + cb * 4 + wn * 2;
                pval[e] = p1; pval[e + 1] = p2;
            }
        }
    }
}

// ---- finalize: per row, exact fp32 rescore of all candidates in margin ----
__global__ __launch_bounds__(256) void som_finalize(
    const float* __restrict__ x, const float* __restrict__ wtf,
    const float* __restrict__ c, const float* __restrict__ loc,
    const float* __restrict__ pval, float* __restrict__ out) {
    const int lane = threadIdx.x & 63;
    const int row = blockIdx.x * 4 + (threadIdx.x >> 6);

    const float4* xr = (const float4*)(x + (size_t)row * Dn);
    float4 xv[4];
    float s2 = 0.f, s1 = 0.f;
    #pragma unroll
    for (int j = 0; j < 4; ++j) {
        xv[j] = xr[lane * 4 + j];
        s2 += xv[j].x * xv[j].x + xv[j].y * xv[j].y + xv[j].z * xv[j].z + xv[j].w * xv[j].w;
        s1 += xv[j].x + xv[j].y + xv[j].z + xv[j].w;
    }
    #pragma unroll
    for (int off = 1; off < 64; off <<= 1) {
        s2 += __shfl_xor(s2, off);
        s1 += __shfl_xor(s1, off);
    }
    const float rrow = s2 + 2.f * EPS * s1 + (float)Dn * EPS * EPS;

    float v0 = pval[(size_t)row * 128 + lane];
    float v1 = pval[(size_t)row * 128 + 64 + lane];
    float g = fminf(v0, v1);
    #pragma unroll
    for (int off = 1; off < 64; off <<= 1) g = fminf(g, __shfl_xor(g, off));
    const float thr = g + 6.0f;   // bf16 noise (15 sigma) + packing error
    unsigned long long m0 = __ballot(v0 <= thr);
    unsigned long long m1 = __ballot(v1 <= thr);

    float bestd2 = 3.4e38f; int bestk = 0x7fffffff;
    #pragma unroll
    for (int slot = 0; slot < 2; ++slot) {
        unsigned long long m = slot ? m1 : m0;
        float vs = slot ? v1 : v0;
        while (m) {
            int src = __builtin_ctzll(m); m &= m - 1;
            int k = ((int)__float_as_uint(__shfl(vs, src))) & 0xFFF;
            const float4* wr = (const float4*)(wtf + (size_t)k * Dn);
            float dt = 0.f;
            #pragma unroll
            for (int j = 0; j < 4; ++j) {
                float4 wv = wr[lane * 4 + j];
                dt += xv[j].x * wv.x + xv[j].y * wv.y + xv[j].z * wv.z + xv[j].w * wv.w;
            }
            #pragma unroll
            for (int off = 1; off < 64; off <<= 1) dt += __shfl_xor(dt, off);
            float d2 = rrow + c[k] - 2.f * dt;
            if (d2 < bestd2 || (d2 == bestd2 && k < bestk)) { bestd2 = d2; bestk = k; }
        }
    }
    if (lane == 0) {
        float dist = sqrtf(fmaxf(bestd2, 0.f));
        out[2 * row]     = loc[2 * bestk];
        out[2 * row + 1] = loc[2 * bestk + 1];
        out[8193 + row]  = (float)bestk;
        atomicAdd(&out[8192], dist * (1.0f / (float)Bn));
    }
}

extern "C" void kernel_launch(void* const* d_in, const int* in_sizes, int n_in,
                              void* d_out, int out_size, void* d_ws, size_t ws_size,
                              hipStream_t stream) {
    const float* x   = (const float*)d_in[0];   // [B, D]
    const float* w   = (const float*)d_in[1];   // [D, K]
    const float* loc = (const float*)d_in[2];   // [K, 2]
    float* out = (float*)d_out;

    float* c    = (float*)d_ws;                          // 16 KB
    float* wtf  = c + Kn;                                // 16 MB  [K][D] fp32
    short* wt   = (short*)(wtf + (size_t)Kn * Dn);       // 8 MB   [K][D] bf16
    short* xb   = wt + (size_t)Kn * Dn;                  // 8 MB   [B][D] bf16
    float* pval = (float*)(xb + (size_t)Bn * Dn);        // 2 MB packed top-2

    som_convert_x<<<(Bn * Dn) / (8 * 256), 256, 0, stream>>>(x, xb, out);
    som_transpose<<<dim3(Kn / 64, Dn / 64), 256, 0, stream>>>(w, wtf, wt);
    som_colstats<<<Kn / 4, 256, 0, stream>>>(wtf, c);
    som_gemm_bf16<<<1024, 256, 0, stream>>>(xb, wt, c, pval);
    som_finalize<<<Bn / 4, 256, 0, stream>>>(x, wtf, c, loc, pval, out);
}

// Round 5
// 199.151 us; speedup vs baseline: 2.9517x; 1.0246x over previous
//
#include <hip/hip_runtime.h>

#define EPS 1e-6f

constexpr int Bn = 4096;   // batch rows
constexpr int Dn = 1024;   // feature dim
constexpr int Kn = 4096;   // codebook entries

typedef __attribute__((ext_vector_type(8))) short short8;   // 8 bf16 (4 VGPRs)
typedef __attribute__((ext_vector_type(4))) float f32x4;    // MFMA accumulator

__device__ inline short f2bf(float f) {            // fp32 -> bf16, RNE
    unsigned u = __float_as_uint(f);
    unsigned r = (u + 0x7FFFu + ((u >> 16) & 1u)) >> 16;
    return (short)r;
}

// pack candidate k (12 bits) into low mantissa of positive score s.
// Monotone in s (|error| <= ~0.25 at s~1000), ties break to smaller k.
__device__ inline float packcand(float s, int k) {
    unsigned b = __float_as_uint(fmaxf(s, 0.5f));
    return __uint_as_float((b & 0xFFFFF000u) | (unsigned)k);
}

#define GLD_LDS16(gp, lp) __builtin_amdgcn_global_load_lds(                  \
    (const __attribute__((address_space(1))) void*)(gp),                     \
    (__attribute__((address_space(3))) void*)(lp), 16, 0, 0)

// ---- fused prep: phase A (bid<2048) x->bf16 + row stats;                  -
// ----             phase B (bid>=2048) w transpose + column-stat partials  -
__global__ __launch_bounds__(256) void som_prep(
    const float* __restrict__ x, const float* __restrict__ w,
    short* __restrict__ xb, float* __restrict__ rrow,
    float* __restrict__ wtf, short* __restrict__ wt,
    float* __restrict__ cpart, float* __restrict__ out) {
    __shared__ float t[64][65];
    __shared__ float cp[4][64];
    __shared__ float red[8];
    const int tid = threadIdx.x;
    const int bid = blockIdx.x;
    if (bid < 2048) {
        if (bid == 0 && tid == 0) out[8192] = 0.f;   // loss accumulator
        const int lane = tid & 63, wid = tid >> 6;
        size_t i = (size_t)bid * 256 + tid;          // 8 elems / thread
        const float4* p = (const float4*)x;
        float4 a = p[i * 2], b = p[i * 2 + 1];
        short8 o;
        o[0] = f2bf(a.x); o[1] = f2bf(a.y); o[2] = f2bf(a.z); o[3] = f2bf(a.w);
        o[4] = f2bf(b.x); o[5] = f2bf(b.y); o[6] = f2bf(b.z); o[7] = f2bf(b.w);
        *(short8*)(xb + i * 8) = o;
        float s2 = a.x*a.x + a.y*a.y + a.z*a.z + a.w*a.w
                 + b.x*b.x + b.y*b.y + b.z*b.z + b.w*b.w;
        float s1 = a.x + a.y + a.z + a.w + b.x + b.y + b.z + b.w;
        #pragma unroll
        for (int off = 1; off < 64; off <<= 1) {
            s2 += __shfl_xor(s2, off);
            s1 += __shfl_xor(s1, off);
        }
        if (lane == 0) { red[wid] = s2; red[4 + wid] = s1; }
        __syncthreads();
        // waves 0,1 cover row bid*2; waves 2,3 cover row bid*2+1
        if (tid == 0)
            rrow[bid * 2] = (red[0] + red[1])
                + 2.f * EPS * (red[4] + red[5]) + (float)Dn * EPS * EPS;
        if (tid == 128)
            rrow[bid * 2 + 1] = (red[2] + red[3])
                + 2.f * EPS * (red[6] + red[7]) + (float)Dn * EPS * EPS;
    } else {
        const int tb = bid - 2048;
        const int kb = tb & 63, db = tb >> 6;        // 64 k-blocks x 16 d-blocks
        const int k0 = kb * 64, d0 = db * 64;
        const int tx = tid & 63, ty = tid >> 6;
        #pragma unroll
        for (int i = 0; i < 16; ++i) {
            int d = i * 4 + ty;
            t[d][tx] = w[(size_t)(d0 + d) * Kn + k0 + tx];   // 256 B coalesced
        }
        __syncthreads();
        #pragma unroll
        for (int i = 0; i < 16; ++i) {
            int kr = i * 4 + ty;
            float v = t[tx][kr];                     // stride 65: conflict-free
            wtf[(size_t)(k0 + kr) * Dn + d0 + tx] = v;
            wt [(size_t)(k0 + kr) * Dn + d0 + tx] = f2bf(v);
        }
        // column-stat partial over this block's 64 d: sum (w^2 - 2 eps w)
        float cs = 0.f;
        #pragma unroll
        for (int j = 0; j < 16; ++j) {
            float v = t[ty * 16 + j][tx];
            cs = fmaf(v, v - 2.f * EPS, cs);
        }
        cp[ty][tx] = cs;
        __syncthreads();
        if (ty == 0)
            cpart[(size_t)db * Kn + k0 + tx] = cp[0][tx] + cp[1][tx] + cp[2][tx] + cp[3][tx];
    }
}

// ---- bf16 MFMA GEMM, fused per-row packed top-2 per 64-col group ----------
// s[b][k] = c[k] - 2 * dot_bf16(xb[b], wt[k]); c[k] summed from cpart slices.
__global__ __launch_bounds__(256) void som_gemm_bf16(
    const short* __restrict__ xb, const short* __restrict__ wt,
    const float* __restrict__ cpart, float* __restrict__ pval) {
    __shared__ short As[128 * 64];   // [row][d] row-major (m97 layout)
    __shared__ short Bs[128 * 64];   // [col][d]
    const int tid = threadIdx.x;
    const int lane = tid & 63;
    const int wid = tid >> 6;
    const int wm = wid >> 1, wn = wid & 1;    // 2x2 waves of 64x64
    const int f = blockIdx.x;
    const int xcd = f & 7;
    const int ib = f >> 3;
    const int rb = xcd * 4 + (ib & 3);
    const int cb = ib >> 2;
    const int rowBase = rb * 128, colBase = cb * 128;

    f32x4 acc[4][4] = {};

    for (int d0 = 0; d0 < Dn; d0 += 64) {
        #pragma unroll
        for (int i = 0; i < 4; ++i) {
            int chunk = i * 256 + tid;
            int r = chunk >> 3, s = chunk & 7;
            GLD_LDS16(xb + (size_t)(rowBase + r) * Dn + d0 + s * 8,
                      &As[(i * 256 + wid * 64) * 8]);
            GLD_LDS16(wt + (size_t)(colBase + r) * Dn + d0 + s * 8,
                      &Bs[(i * 256 + wid * 64) * 8]);
        }
        __syncthreads();
        const int mr = wm * 64 + (lane & 15);
        const int nr = wn * 64 + (lane & 15);
        const int q = lane >> 4;
        #pragma unroll
        for (int kk = 0; kk < 2; ++kk) {
            short8 a[4], b[4];
            #pragma unroll
            for (int i = 0; i < 4; ++i) {
                a[i] = *(const short8*)&As[(mr + i * 16) * 64 + (kk * 4 + q) * 8];
                b[i] = *(const short8*)&Bs[(nr + i * 16) * 64 + (kk * 4 + q) * 8];
            }
            #pragma unroll
            for (int i = 0; i < 4; ++i)
                #pragma unroll
                for (int j = 0; j < 4; ++j)
                    acc[i][j] = __builtin_amdgcn_mfma_f32_16x16x32_bf16(
                        a[i], b[j], acc[i][j], 0, 0, 0);
        }
        __syncthreads();
    }

    // epilogue: c[k] from cpart, then packed top-2 per (row, 64-col group)
    const int cn = lane & 15, q = lane >> 4;
    const int nbase = colBase + wn * 64;
    float cv[4];
    #pragma unroll
    for (int j = 0; j < 4; ++j) {
        float s = 0.f;
        #pragma unroll
        for (int db = 0; db < 16; ++db)
            s += cpart[(size_t)db * Kn + nbase + j * 16 + cn];
        cv[j] = s;
    }
    #pragma unroll
    for (int i = 0; i < 4; ++i) {
        #pragma unroll
        for (int rg = 0; rg < 4; ++rg) {
            float p1 = 3.4e38f, p2 = 3.4e38f;
            #pragma unroll
            for (int j = 0; j < 4; ++j) {
                float p = packcand(fmaf(-2.f, acc[i][j][rg], cv[j]),
                                   nbase + j * 16 + cn);
                float lo = fminf(p1, p), hi = fmaxf(p1, p);
                p1 = lo; p2 = fminf(p2, hi);
            }
            #pragma unroll
            for (int off = 1; off < 16; off <<= 1) {
                float o1 = __shfl_xor(p1, off);
                float o2 = __shfl_xor(p2, off);
                float lo = fminf(p1, o1), hi = fmaxf(p1, o1);
                p1 = lo; p2 = fminf(hi, fminf(p2, o2));
            }
            if (cn == 0) {
                int mrow = rowBase + wm * 64 + i * 16 + q * 4 + rg;
                size_t e = (size_t)mrow * 128 + cb * 4 + wn * 2;
                pval[e] = p1; pval[e + 1] = p2;
            }
        }
    }
}

// ---- finalize: per row, exact fp32 rescore of all candidates in margin ----
__global__ __launch_bounds__(256) void som_finalize(
    const float* __restrict__ x, const float* __restrict__ wtf,
    const float* __restrict__ cpart, const float* __restrict__ loc,
    const float* __restrict__ pval, const float* __restrict__ rrow,
    float* __restrict__ out) {
    const int lane = threadIdx.x & 63;
    const int row = blockIdx.x * 4 + (threadIdx.x >> 6);

    const float4* xr = (const float4*)(x + (size_t)row * Dn);
    float4 xv[4];
    #pragma unroll
    for (int j = 0; j < 4; ++j) xv[j] = xr[lane * 4 + j];
    const float rrv = rrow[row];

    float v0 = pval[(size_t)row * 128 + lane];
    float v1 = pval[(size_t)row * 128 + 64 + lane];
    float g = fminf(v0, v1);
    #pragma unroll
    for (int off = 1; off < 64; off <<= 1) g = fminf(g, __shfl_xor(g, off));
    const float thr = g + 6.0f;   // bf16 noise (15 sigma) + packing error
    unsigned long long m0 = __ballot(v0 <= thr);
    unsigned long long m1 = __ballot(v1 <= thr);

    float bestd2 = 3.4e38f; int bestk = 0x7fffffff;
    #pragma unroll
    for (int slot = 0; slot < 2; ++slot) {
        unsigned long long m = slot ? m1 : m0;
        float vs = slot ? v1 : v0;
        while (m) {
            int src = __builtin_ctzll(m); m &= m - 1;
            int k = ((int)__float_as_uint(__shfl(vs, src))) & 0xFFF;
            const float4* wr = (const float4*)(wtf + (size_t)k * Dn);
            float dt = 0.f;
            #pragma unroll
            for (int j = 0; j < 4; ++j) {
                float4 wv = wr[lane * 4 + j];
                dt += xv[j].x * wv.x + xv[j].y * wv.y + xv[j].z * wv.z + xv[j].w * wv.w;
            }
            #pragma unroll
            for (int off = 1; off < 64; off <<= 1) dt += __shfl_xor(dt, off);
            float ck = 0.f;
            #pragma unroll
            for (int db = 0; db < 16; ++db) ck += cpart[(size_t)db * Kn + k];
            float d2 = rrv + ck - 2.f * dt;
            if (d2 < bestd2 || (d2 == bestd2 && k < bestk)) { bestd2 = d2; bestk = k; }
        }
    }
    if (lane == 0) {
        float dist = sqrtf(fmaxf(bestd2, 0.f));
        out[2 * row]     = loc[2 * bestk];
        out[2 * row + 1] = loc[2 * bestk + 1];
        out[8193 + row]  = (float)bestk;
        atomicAdd(&out[8192], dist * (1.0f / (float)Bn));
    }
}

extern "C" void kernel_launch(void* const* d_in, const int* in_sizes, int n_in,
                              void* d_out, int out_size, void* d_ws, size_t ws_size,
                              hipStream_t stream) {
    const float* x   = (const float*)d_in[0];   // [B, D]
    const float* w   = (const float*)d_in[1];   // [D, K]
    const float* loc = (const float*)d_in[2];   // [K, 2]
    float* out = (float*)d_out;

    float* rrow = (float*)d_ws;                          // 16 KB  [B]
    float* wtf  = rrow + Bn;                             // 16 MB  [K][D] fp32
    short* wt   = (short*)(wtf + (size_t)Kn * Dn);       // 8 MB   [K][D] bf16
    short* xb   = wt + (size_t)Kn * Dn;                  // 8 MB   [B][D] bf16
    float* pval = (float*)(xb + (size_t)Bn * Dn);        // 2 MB packed top-2
    float* cpart = pval + (size_t)Bn * 128;              // 256 KB [16][K]

    som_prep<<<3072, 256, 0, stream>>>(x, w, xb, rrow, wtf, wt, cpart, out);
    som_gemm_bf16<<<1024, 256, 0, stream>>>(xb, wt, cpart, pval);
    som_finalize<<<Bn / 4, 256, 0, stream>>>(x, wtf, cpart, loc, pval, rrow, out);
}

// Round 6
// 189.300 us; speedup vs baseline: 3.1053x; 1.0520x over previous
//
#include <hip/hip_runtime.h>

#define EPS 1e-6f

constexpr int Bn = 4096;   // batch rows
constexpr int Dn = 1024;   // feature dim
constexpr int Kn = 4096;   // codebook entries

typedef __attribute__((ext_vector_type(8))) short short8;   // 8 bf16 (4 VGPRs)
typedef __attribute__((ext_vector_type(4))) float f32x4;    // MFMA accumulator

__device__ inline short f2bf(float f) {            // fp32 -> bf16, RNE
    unsigned u = __float_as_uint(f);
    unsigned r = (u + 0x7FFFu + ((u >> 16) & 1u)) >> 16;
    return (short)r;
}

// pack candidate k (12 bits) into low mantissa of positive score s.
// Monotone in s (|error| <= ~0.25 at s~1000), ties break to smaller k.
__device__ inline float packcand(float s, int k) {
    unsigned b = __float_as_uint(fmaxf(s, 0.5f));
    return __uint_as_float((b & 0xFFFFF000u) | (unsigned)k);
}

// ---- fused prep: phase A (bid<2048) x->bf16 + row stats;                  -
// ----             phase B (bid>=2048) w transpose + column-stat partials  -
__global__ __launch_bounds__(256) void som_prep(
    const float* __restrict__ x, const float* __restrict__ w,
    short* __restrict__ xb, float* __restrict__ rrow,
    float* __restrict__ wtf, short* __restrict__ wt,
    float* __restrict__ cpart, float* __restrict__ out) {
    __shared__ float t[64][65];
    __shared__ float cp[4][64];
    __shared__ float red[8];
    const int tid = threadIdx.x;
    const int bid = blockIdx.x;
    if (bid < 2048) {
        if (bid == 0 && tid == 0) out[8192] = 0.f;   // loss accumulator
        const int lane = tid & 63, wid = tid >> 6;
        size_t i = (size_t)bid * 256 + tid;          // 8 elems / thread
        const float4* p = (const float4*)x;
        float4 a = p[i * 2], b = p[i * 2 + 1];
        short8 o;
        o[0] = f2bf(a.x); o[1] = f2bf(a.y); o[2] = f2bf(a.z); o[3] = f2bf(a.w);
        o[4] = f2bf(b.x); o[5] = f2bf(b.y); o[6] = f2bf(b.z); o[7] = f2bf(b.w);
        *(short8*)(xb + i * 8) = o;
        float s2 = a.x*a.x + a.y*a.y + a.z*a.z + a.w*a.w
                 + b.x*b.x + b.y*b.y + b.z*b.z + b.w*b.w;
        float s1 = a.x + a.y + a.z + a.w + b.x + b.y + b.z + b.w;
        #pragma unroll
        for (int off = 1; off < 64; off <<= 1) {
            s2 += __shfl_xor(s2, off);
            s1 += __shfl_xor(s1, off);
        }
        if (lane == 0) { red[wid] = s2; red[4 + wid] = s1; }
        __syncthreads();
        // waves 0,1 cover row bid*2; waves 2,3 cover row bid*2+1
        if (tid == 0)
            rrow[bid * 2] = (red[0] + red[1])
                + 2.f * EPS * (red[4] + red[5]) + (float)Dn * EPS * EPS;
        if (tid == 128)
            rrow[bid * 2 + 1] = (red[2] + red[3])
                + 2.f * EPS * (red[6] + red[7]) + (float)Dn * EPS * EPS;
    } else {
        const int tb = bid - 2048;
        const int kb = tb & 63, db = tb >> 6;        // 64 k-blocks x 16 d-blocks
        const int k0 = kb * 64, d0 = db * 64;
        const int tx = tid & 63, ty = tid >> 6;
        #pragma unroll
        for (int i = 0; i < 16; ++i) {
            int d = i * 4 + ty;
            t[d][tx] = w[(size_t)(d0 + d) * Kn + k0 + tx];   // 256 B coalesced
        }
        __syncthreads();
        #pragma unroll
        for (int i = 0; i < 16; ++i) {
            int kr = i * 4 + ty;
            float v = t[tx][kr];                     // stride 65: conflict-free
            wtf[(size_t)(k0 + kr) * Dn + d0 + tx] = v;
            wt [(size_t)(k0 + kr) * Dn + d0 + tx] = f2bf(v);
        }
        // column-stat partial over this block's 64 d: sum (w^2 - 2 eps w)
        float cs = 0.f;
        #pragma unroll
        for (int j = 0; j < 16; ++j) {
            float v = t[ty * 16 + j][tx];
            cs = fmaf(v, v - 2.f * EPS, cs);
        }
        cp[ty][tx] = cs;
        __syncthreads();
        if (ty == 0)
            cpart[(size_t)db * Kn + k0 + tx] = cp[0][tx] + cp[1][tx] + cp[2][tx] + cp[3][tx];
    }
}

// ---- bf16 MFMA GEMM, manual staging + XOR-swizzled LDS (conflict-free) ----
// s[b][k] = c[k] - 2 * dot_bf16(xb[b], wt[k]); c[k] summed from cpart slices.
// LDS addr for 16B granule (row, seg): row*128 + (seg^(row&7))*16 — writes
// cover full 128B rows (all banks), fragment reads spread 2 lanes/bank-group.
__global__ __launch_bounds__(256) void som_gemm_bf16(
    const short* __restrict__ xb, const short* __restrict__ wt,
    const float* __restrict__ cpart, float* __restrict__ pval) {
    __shared__ short As[128 * 64];   // swizzled [row][seg'] granules
    __shared__ short Bs[128 * 64];
    const int tid = threadIdx.x;
    const int lane = tid & 63;
    const int wid = tid >> 6;
    const int wm = wid >> 1, wn = wid & 1;    // 2x2 waves of 64x64
    const int f = blockIdx.x;
    const int xcd = f & 7;
    const int ib = f >> 3;
    const int rb = xcd * 4 + (ib & 3);
    const int cb = ib >> 2;
    const int rowBase = rb * 128, colBase = cb * 128;

    // staging granule meta: g = i*256 + tid -> (row, seg); global coalesced
    int ldsoff[4];
    const short* gsrcA[4];
    const short* gsrcB[4];
    #pragma unroll
    for (int i = 0; i < 4; ++i) {
        int g = i * 256 + tid;
        int r = g >> 3, s = g & 7;
        ldsoff[i] = r * 64 + ((s ^ (r & 7)) << 3);          // in shorts
        gsrcA[i] = xb + (size_t)(rowBase + r) * Dn + s * 8;
        gsrcB[i] = wt + (size_t)(colBase + r) * Dn + s * 8;
    }

    f32x4 acc[4][4] = {};
    short8 ra[4], rbv[4];
    #pragma unroll
    for (int i = 0; i < 4; ++i) {            // prefetch iter 0
        ra[i]  = *(const short8*)(gsrcA[i]);
        rbv[i] = *(const short8*)(gsrcB[i]);
    }

    for (int it = 0; it < 16; ++it) {
        #pragma unroll
        for (int i = 0; i < 4; ++i) {
            *(short8*)&As[ldsoff[i]] = ra[i];
            *(short8*)&Bs[ldsoff[i]] = rbv[i];
        }
        __syncthreads();
        if (it < 15) {                        // prefetch next iter's globals
            int d0 = (it + 1) * 64;
            #pragma unroll
            for (int i = 0; i < 4; ++i) {
                ra[i]  = *(const short8*)(gsrcA[i] + d0);
                rbv[i] = *(const short8*)(gsrcB[i] + d0);
            }
        }
        const int mr = wm * 64 + (lane & 15);
        const int nr = wn * 64 + (lane & 15);
        const int q = lane >> 4;
        const int lx = lane & 7;              // row&7 for both A and B frags
        #pragma unroll
        for (int kk = 0; kk < 2; ++kk) {
            const int sg = (kk * 4 + q) ^ lx;
            short8 a[4], b[4];
            #pragma unroll
            for (int i = 0; i < 4; ++i) {
                a[i] = *(const short8*)&As[(mr + i * 16) * 64 + sg * 8];
                b[i] = *(const short8*)&Bs[(nr + i * 16) * 64 + sg * 8];
            }
            #pragma unroll
            for (int i = 0; i < 4; ++i)
                #pragma unroll
                for (int j = 0; j < 4; ++j)
                    acc[i][j] = __builtin_amdgcn_mfma_f32_16x16x32_bf16(
                        a[i], b[j], acc[i][j], 0, 0, 0);
        }
        __syncthreads();
    }

    // epilogue: c[k] from cpart, then packed top-2 per (row, 64-col group)
    const int cn = lane & 15, q = lane >> 4;
    const int nbase = colBase + wn * 64;
    float cv[4];
    #pragma unroll
    for (int j = 0; j < 4; ++j) {
        float s = 0.f;
        #pragma unroll
        for (int db = 0; db < 16; ++db)
            s += cpart[(size_t)db * Kn + nbase + j * 16 + cn];
        cv[j] = s;
    }
    #pragma unroll
    for (int i = 0; i < 4; ++i) {
        #pragma unroll
        for (int rg = 0; rg < 4; ++rg) {
            float p1 = 3.4e38f, p2 = 3.4e38f;
            #pragma unroll
            for (int j = 0; j < 4; ++j) {
                float p = packcand(fmaf(-2.f, acc[i][j][rg], cv[j]),
                                   nbase + j * 16 + cn);
                float lo = fminf(p1, p), hi = fmaxf(p1, p);
                p1 = lo; p2 = fminf(p2, hi);
            }
            #pragma unroll
            for (int off = 1; off < 16; off <<= 1) {
                float o1 = __shfl_xor(p1, off);
                float o2 = __shfl_xor(p2, off);
                float lo = fminf(p1, o1), hi = fmaxf(p1, o1);
                p1 = lo; p2 = fminf(hi, fminf(p2, o2));
            }
            if (cn == 0) {
                int mrow = rowBase + wm * 64 + i * 16 + q * 4 + rg;
                size_t e = (size_t)mrow * 128 + cb * 4 + wn * 2;
                pval[e] = p1; pval[e + 1] = p2;
            }
        }
    }
}

// ---- finalize: per row, exact fp32 rescore of all candidates in margin ----
__global__ __launch_bounds__(256) void som_finalize(
    const float* __restrict__ x, const float* __restrict__ wtf,
    const float* __restrict__ cpart, const float* __restrict__ loc,
    const float* __restrict__ pval, const float* __restrict__ rrow,
    float* __restrict__ out) {
    const int lane = threadIdx.x & 63;
    const int row = blockIdx.x * 4 + (threadIdx.x >> 6);

    const float4* xr = (const float4*)(x + (size_t)row * Dn);
    float4 xv[4];
    #pragma unroll
    for (int j = 0; j < 4; ++j) xv[j] = xr[lane * 4 + j];
    const float rrv = rrow[row];

    float v0 = pval[(size_t)row * 128 + lane];
    float v1 = pval[(size_t)row * 128 + 64 + lane];
    float g = fminf(v0, v1);
    #pragma unroll
    for (int off = 1; off < 64; off <<= 1) g = fminf(g, __shfl_xor(g, off));
    const float thr = g + 6.0f;   // bf16 noise (15 sigma) + packing error
    unsigned long long m0 = __ballot(v0 <= thr);
    unsigned long long m1 = __ballot(v1 <= thr);

    float bestd2 = 3.4e38f; int bestk = 0x7fffffff;
    #pragma unroll
    for (int slot = 0; slot < 2; ++slot) {
        unsigned long long m = slot ? m1 : m0;
        float vs = slot ? v1 : v0;
        while (m) {
            int src = __builtin_ctzll(m); m &= m - 1;
            int k = ((int)__float_as_uint(__shfl(vs, src))) & 0xFFF;
            const float4* wr = (const float4*)(wtf + (size_t)k * Dn);
            float dt = 0.f;
            #pragma unroll
            for (int j = 0; j < 4; ++j) {
                float4 wv = wr[lane * 4 + j];
                dt += xv[j].x * wv.x + xv[j].y * wv.y + xv[j].z * wv.z + xv[j].w * wv.w;
            }
            #pragma unroll
            for (int off = 1; off < 64; off <<= 1) dt += __shfl_xor(dt, off);
            float ck = 0.f;
            #pragma unroll
            for (int db = 0; db < 16; ++db) ck += cpart[(size_t)db * Kn + k];
            float d2 = rrv + ck - 2.f * dt;
            if (d2 < bestd2 || (d2 == bestd2 && k < bestk)) { bestd2 = d2; bestk = k; }
        }
    }
    if (lane == 0) {
        float dist = sqrtf(fmaxf(bestd2, 0.f));
        out[2 * row]     = loc[2 * bestk];
        out[2 * row + 1] = loc[2 * bestk + 1];
        out[8193 + row]  = (float)bestk;
        atomicAdd(&out[8192], dist * (1.0f / (float)Bn));
    }
}

extern "C" void kernel_launch(void* const* d_in, const int* in_sizes, int n_in,
                              void* d_out, int out_size, void* d_ws, size_t ws_size,
                              hipStream_t stream) {
    const float* x   = (const float*)d_in[0];   // [B, D]
    const float* w   = (const float*)d_in[1];   // [D, K]
    const float* loc = (const float*)d_in[2];   // [K, 2]
    float* out = (float*)d_out;

    float* rrow = (float*)d_ws;                          // 16 KB  [B]
    float* wtf  = rrow + Bn;                             // 16 MB  [K][D] fp32
    short* wt   = (short*)(wtf + (size_t)Kn * Dn);       // 8 MB   [K][D] bf16
    short* xb   = wt + (size_t)Kn * Dn;                  // 8 MB   [B][D] bf16
    float* pval = (float*)(xb + (size_t)Bn * Dn);        // 2 MB packed top-2
    float* cpart = pval + (size_t)Bn * 128;              // 256 KB [16][K]

    som_prep<<<3072, 256, 0, stream>>>(x, w, xb, rrow, wtf, wt, cpart, out);
    som_gemm_bf16<<<1024, 256, 0, stream>>>(xb, wt, cpart, pval);
    som_finalize<<<Bn / 4, 256, 0, stream>>>(x, wtf, cpart, loc, pval, rrow, out);
}

// Round 7
// 144.074 us; speedup vs baseline: 4.0801x; 1.3139x over previous
//
#include <hip/hip_runtime.h>

#define EPS 1e-6f

constexpr int Bn = 4096;   // batch rows
constexpr int Dn = 1024;   // feature dim
constexpr int Kn = 4096;   // codebook entries

typedef __attribute__((ext_vector_type(8))) short short8;   // 8 bf16 (4 VGPRs)
typedef __attribute__((ext_vector_type(4))) float f32x4;    // MFMA accumulator

__device__ inline short f2bf(float f) {            // fp32 -> bf16, RNE
    unsigned u = __float_as_uint(f);
    unsigned r = (u + 0x7FFFu + ((u >> 16) & 1u)) >> 16;
    return (short)r;
}

// pack candidate k (12 bits) into low mantissa of positive score s.
// Monotone in s (|error| <= ~0.5 at s~1000), ties break to smaller k.
__device__ inline float packcand(float s, int k) {
    unsigned b = __float_as_uint(fmaxf(s, 0.5f));
    return __uint_as_float((b & 0xFFFFF000u) | (unsigned)k);
}

// ---- fused prep: phase A (bid<2048) x->bf16 + row stats;                  -
// ----             phase B (bid>=2048) w transpose + column-stat partials  -
__global__ __launch_bounds__(256) void som_prep(
    const float* __restrict__ x, const float* __restrict__ w,
    short* __restrict__ xb, float* __restrict__ rrow,
    float* __restrict__ wtf, short* __restrict__ wt,
    float* __restrict__ cpart) {
    __shared__ float t[64][65];
    __shared__ float cp[4][64];
    __shared__ float red[8];
    const int tid = threadIdx.x;
    const int bid = blockIdx.x;
    if (bid < 2048) {
        const int lane = tid & 63, wid = tid >> 6;
        size_t i = (size_t)bid * 256 + tid;          // 8 elems / thread
        const float4* p = (const float4*)x;
        float4 a = p[i * 2], b = p[i * 2 + 1];
        short8 o;
        o[0] = f2bf(a.x); o[1] = f2bf(a.y); o[2] = f2bf(a.z); o[3] = f2bf(a.w);
        o[4] = f2bf(b.x); o[5] = f2bf(b.y); o[6] = f2bf(b.z); o[7] = f2bf(b.w);
        *(short8*)(xb + i * 8) = o;
        float s2 = a.x*a.x + a.y*a.y + a.z*a.z + a.w*a.w
                 + b.x*b.x + b.y*b.y + b.z*b.z + b.w*b.w;
        float s1 = a.x + a.y + a.z + a.w + b.x + b.y + b.z + b.w;
        #pragma unroll
        for (int off = 1; off < 64; off <<= 1) {
            s2 += __shfl_xor(s2, off);
            s1 += __shfl_xor(s1, off);
        }
        if (lane == 0) { red[wid] = s2; red[4 + wid] = s1; }
        __syncthreads();
        // waves 0,1 cover row bid*2; waves 2,3 cover row bid*2+1
        if (tid == 0)
            rrow[bid * 2] = (red[0] + red[1])
                + 2.f * EPS * (red[4] + red[5]) + (float)Dn * EPS * EPS;
        if (tid == 128)
            rrow[bid * 2 + 1] = (red[2] + red[3])
                + 2.f * EPS * (red[6] + red[7]) + (float)Dn * EPS * EPS;
    } else {
        const int tb = bid - 2048;
        const int kb = tb & 63, db = tb >> 6;        // 64 k-blocks x 16 d-blocks
        const int k0 = kb * 64, d0 = db * 64;
        const int tx = tid & 63, ty = tid >> 6;
        #pragma unroll
        for (int i = 0; i < 16; ++i) {
            int d = i * 4 + ty;
            t[d][tx] = w[(size_t)(d0 + d) * Kn + k0 + tx];   // 256 B coalesced
        }
        __syncthreads();
        #pragma unroll
        for (int i = 0; i < 16; ++i) {
            int kr = i * 4 + ty;
            float v = t[tx][kr];                     // stride 65: conflict-free
            wtf[(size_t)(k0 + kr) * Dn + d0 + tx] = v;
            wt [(size_t)(k0 + kr) * Dn + d0 + tx] = f2bf(v);
        }
        // column-stat partial over this block's 64 d: sum (w^2 - 2 eps w)
        float cs = 0.f;
        #pragma unroll
        for (int j = 0; j < 16; ++j) {
            float v = t[ty * 16 + j][tx];
            cs = fmaf(v, v - 2.f * EPS, cs);
        }
        cp[ty][tx] = cs;
        __syncthreads();
        if (ty == 0)
            cpart[(size_t)db * Kn + k0 + tx] = cp[0][tx] + cp[1][tx] + cp[2][tx] + cp[3][tx];
    }
}

// ---- bf16 MFMA GEMM, manual staging + XOR-swizzled LDS (conflict-free) ----
// s[b][k] = c[k] - 2 * dot_bf16(xb[b], wt[k]); c[k] summed from cpart slices.
// LDS addr for 16B granule (row, seg): row*128 + (seg^(row&7))*16 — writes
// cover full 128B rows (all banks), fragment reads spread 2 lanes/bank-group.
__global__ __launch_bounds__(256) void som_gemm_bf16(
    const short* __restrict__ xb, const short* __restrict__ wt,
    const float* __restrict__ cpart, float* __restrict__ pval) {
    __shared__ short As[128 * 64];   // swizzled [row][seg'] granules
    __shared__ short Bs[128 * 64];
    const int tid = threadIdx.x;
    const int lane = tid & 63;
    const int wid = tid >> 6;
    const int wm = wid >> 1, wn = wid & 1;    // 2x2 waves of 64x64
    const int f = blockIdx.x;
    const int xcd = f & 7;
    const int ib = f >> 3;
    const int rb = xcd * 4 + (ib & 3);
    const int cb = ib >> 2;
    const int rowBase = rb * 128, colBase = cb * 128;

    // staging granule meta: g = i*256 + tid -> (row, seg); global coalesced
    int ldsoff[4];
    const short* gsrcA[4];
    const short* gsrcB[4];
    #pragma unroll
    for (int i = 0; i < 4; ++i) {
        int g = i * 256 + tid;
        int r = g >> 3, s = g & 7;
        ldsoff[i] = r * 64 + ((s ^ (r & 7)) << 3);          // in shorts
        gsrcA[i] = xb + (size_t)(rowBase + r) * Dn + s * 8;
        gsrcB[i] = wt + (size_t)(colBase + r) * Dn + s * 8;
    }

    f32x4 acc[4][4] = {};
    short8 ra[4], rbv[4];
    #pragma unroll
    for (int i = 0; i < 4; ++i) {            // prefetch iter 0
        ra[i]  = *(const short8*)(gsrcA[i]);
        rbv[i] = *(const short8*)(gsrcB[i]);
    }

    for (int it = 0; it < 16; ++it) {
        #pragma unroll
        for (int i = 0; i < 4; ++i) {
            *(short8*)&As[ldsoff[i]] = ra[i];
            *(short8*)&Bs[ldsoff[i]] = rbv[i];
        }
        __syncthreads();
        if (it < 15) {                        // prefetch next iter's globals
            int d0 = (it + 1) * 64;
            #pragma unroll
            for (int i = 0; i < 4; ++i) {
                ra[i]  = *(const short8*)(gsrcA[i] + d0);
                rbv[i] = *(const short8*)(gsrcB[i] + d0);
            }
        }
        const int mr = wm * 64 + (lane & 15);
        const int nr = wn * 64 + (lane & 15);
        const int q = lane >> 4;
        const int lx = lane & 7;              // row&7 for both A and B frags
        #pragma unroll
        for (int kk = 0; kk < 2; ++kk) {
            const int sg = (kk * 4 + q) ^ lx;
            short8 a[4], b[4];
            #pragma unroll
            for (int i = 0; i < 4; ++i) {
                a[i] = *(const short8*)&As[(mr + i * 16) * 64 + sg * 8];
                b[i] = *(const short8*)&Bs[(nr + i * 16) * 64 + sg * 8];
            }
            #pragma unroll
            for (int i = 0; i < 4; ++i)
                #pragma unroll
                for (int j = 0; j < 4; ++j)
                    acc[i][j] = __builtin_amdgcn_mfma_f32_16x16x32_bf16(
                        a[i], b[j], acc[i][j], 0, 0, 0);
        }
        __syncthreads();
    }

    // epilogue: c[k] from cpart, then packed top-2 per (row, 64-col group)
    const int cn = lane & 15, q = lane >> 4;
    const int nbase = colBase + wn * 64;
    float cv[4];
    #pragma unroll
    for (int j = 0; j < 4; ++j) {
        float s = 0.f;
        #pragma unroll
        for (int db = 0; db < 16; ++db)
            s += cpart[(size_t)db * Kn + nbase + j * 16 + cn];
        cv[j] = s;
    }
    #pragma unroll
    for (int i = 0; i < 4; ++i) {
        #pragma unroll
        for (int rg = 0; rg < 4; ++rg) {
            float p1 = 3.4e38f, p2 = 3.4e38f;
            #pragma unroll
            for (int j = 0; j < 4; ++j) {
                float p = packcand(fmaf(-2.f, acc[i][j][rg], cv[j]),
                                   nbase + j * 16 + cn);
                float lo = fminf(p1, p), hi = fmaxf(p1, p);
                p1 = lo; p2 = fminf(p2, hi);
            }
            #pragma unroll
            for (int off = 1; off < 16; off <<= 1) {
                float o1 = __shfl_xor(p1, off);
                float o2 = __shfl_xor(p2, off);
                float lo = fminf(p1, o1), hi = fmaxf(p1, o1);
                p1 = lo; p2 = fminf(hi, fminf(p2, o2));
            }
            if (cn == 0) {
                int mrow = rowBase + wm * 64 + i * 16 + q * 4 + rg;
                size_t e = (size_t)mrow * 128 + cb * 4 + wn * 2;
                pval[e] = p1; pval[e + 1] = p2;
            }
        }
    }
}

// ---- finalize: per row, exact fp32 rescore of all candidates in margin ----
// Writes dist[row] to workspace (NO same-address atomic — that serialized
// 4096 waves at ~36 cyc each = 61 us in R6).
__global__ __launch_bounds__(256) void som_finalize(
    const float* __restrict__ x, const float* __restrict__ wtf,
    const float* __restrict__ cpart, const float* __restrict__ loc,
    const float* __restrict__ pval, const float* __restrict__ rrow,
    float* __restrict__ dist, float* __restrict__ out) {
    const int lane = threadIdx.x & 63;
    const int row = blockIdx.x * 4 + (threadIdx.x >> 6);

    const float4* xr = (const float4*)(x + (size_t)row * Dn);
    float4 xv[4];
    #pragma unroll
    for (int j = 0; j < 4; ++j) xv[j] = xr[lane * 4 + j];
    const float rrv = rrow[row];

    float v0 = pval[(size_t)row * 128 + lane];
    float v1 = pval[(size_t)row * 128 + 64 + lane];
    float g = fminf(v0, v1);
    #pragma unroll
    for (int off = 1; off < 64; off <<= 1) g = fminf(g, __shfl_xor(g, off));
    const float thr = g + 6.0f;   // bf16 noise (15 sigma) + packing error
    unsigned long long m0 = __ballot(v0 <= thr);
    unsigned long long m1 = __ballot(v1 <= thr);

    float bestd2 = 3.4e38f; int bestk = 0x7fffffff;
    #pragma unroll
    for (int slot = 0; slot < 2; ++slot) {
        unsigned long long m = slot ? m1 : m0;
        float vs = slot ? v1 : v0;
        while (m) {
            int src = __builtin_ctzll(m); m &= m - 1;
            int k = ((int)__float_as_uint(__shfl(vs, src))) & 0xFFF;
            const float4* wr = (const float4*)(wtf + (size_t)k * Dn);
            float dt = 0.f;
            #pragma unroll
            for (int j = 0; j < 4; ++j) {
                float4 wv = wr[lane * 4 + j];
                dt += xv[j].x * wv.x + xv[j].y * wv.y + xv[j].z * wv.z + xv[j].w * wv.w;
            }
            #pragma unroll
            for (int off = 1; off < 64; off <<= 1) dt += __shfl_xor(dt, off);
            float ck = 0.f;
            #pragma unroll
            for (int db = 0; db < 16; ++db) ck += cpart[(size_t)db * Kn + k];
            float d2 = rrv + ck - 2.f * dt;
            if (d2 < bestd2 || (d2 == bestd2 && k < bestk)) { bestd2 = d2; bestk = k; }
        }
    }
    if (lane == 0) {
        out[2 * row]     = loc[2 * bestk];
        out[2 * row + 1] = loc[2 * bestk + 1];
        out[8193 + row]  = (float)bestk;
        dist[row]        = sqrtf(fmaxf(bestd2, 0.f));
    }
}

// ---- loss: single block reduces the 4096 per-row distances ----------------
__global__ __launch_bounds__(256) void som_loss(const float* __restrict__ dist,
                                                float* __restrict__ out) {
    __shared__ float red[4];
    const int tid = threadIdx.x;
    const int lane = tid & 63, wid = tid >> 6;
    const float4* p = (const float4*)dist;
    float s = 0.f;
    #pragma unroll
    for (int j = 0; j < 4; ++j) {
        float4 v = p[tid + j * 256];
        s += v.x + v.y + v.z + v.w;
    }
    #pragma unroll
    for (int off = 1; off < 64; off <<= 1) s += __shfl_xor(s, off);
    if (lane == 0) red[wid] = s;
    __syncthreads();
    if (tid == 0)
        out[8192] = (red[0] + red[1] + red[2] + red[3]) * (1.0f / (float)Bn);
}

extern "C" void kernel_launch(void* const* d_in, const int* in_sizes, int n_in,
                              void* d_out, int out_size, void* d_ws, size_t ws_size,
                              hipStream_t stream) {
    const float* x   = (const float*)d_in[0];   // [B, D]
    const float* w   = (const float*)d_in[1];   // [D, K]
    const float* loc = (const float*)d_in[2];   // [K, 2]
    float* out = (float*)d_out;

    float* rrow = (float*)d_ws;                          // 16 KB  [B]
    float* wtf  = rrow + Bn;                             // 16 MB  [K][D] fp32
    short* wt   = (short*)(wtf + (size_t)Kn * Dn);       // 8 MB   [K][D] bf16
    short* xb   = wt + (size_t)Kn * Dn;                  // 8 MB   [B][D] bf16
    float* pval = (float*)(xb + (size_t)Bn * Dn);        // 2 MB packed top-2
    float* cpart = pval + (size_t)Bn * 128;              // 256 KB [16][K]
    float* dist  = cpart + 16 * Kn;                      // 16 KB  [B]

    som_prep<<<3072, 256, 0, stream>>>(x, w, xb, rrow, wtf, wt, cpart);
    som_gemm_bf16<<<1024, 256, 0, stream>>>(xb, wt, cpart, pval);
    som_finalize<<<Bn / 4, 256, 0, stream>>>(x, wtf, cpart, loc, pval, rrow, dist, out);
    som_loss<<<1, 256, 0, stream>>>(dist, out);
}

// Round 9
// 141.466 us; speedup vs baseline: 4.1553x; 1.0184x over previous
//
#include <hip/hip_runtime.h>

#define EPS 1e-6f

constexpr int Bn = 4096;   // batch rows
constexpr int Dn = 1024;   // feature dim
constexpr int Kn = 4096;   // codebook entries

typedef __attribute__((ext_vector_type(4))) float f32x4;      // MFMA accumulator
typedef __attribute__((ext_vector_type(2))) long long ll2;    // 16B = 2 fp8 k-slices

// 'hi' operand of cvt_pk_fp8 must be an immediate — two literal wrappers.
__device__ inline int pk_fp8_lo(float a, float b, int old) {
    return __builtin_amdgcn_cvt_pk_fp8_f32(a, b, old, false);  // HW RNE e4m3
}
__device__ inline int pk_fp8_hi(float a, float b, int old) {
    return __builtin_amdgcn_cvt_pk_fp8_f32(a, b, old, true);
}

// pack candidate k (12 bits) into low mantissa of positive score s.
// Monotone in s (|error| <= ~1 at s~2048), ties break to smaller k.
__device__ inline float packcand(float s, int k) {
    unsigned b = __float_as_uint(fmaxf(s, 0.5f));
    return __uint_as_float((b & 0xFFFFF000u) | (unsigned)k);
}

// ---- fused prep: phase A (bid<2048) x->fp8 + row stats;                   -
// ----             phase B (bid>=2048) w transpose (fp32 + fp8) + col stats -
__global__ __launch_bounds__(256) void som_prep(
    const float* __restrict__ x, const float* __restrict__ w,
    unsigned char* __restrict__ xf8, float* __restrict__ rrow,
    float* __restrict__ wtf, unsigned char* __restrict__ wf8,
    float* __restrict__ cpart) {
    __shared__ float t[64][65];
    __shared__ float cp[4][64];
    __shared__ float red[8];
    const int tid = threadIdx.x;
    const int bid = blockIdx.x;
    if (bid < 2048) {
        const int lane = tid & 63, wid = tid >> 6;
        size_t i = (size_t)bid * 256 + tid;          // 8 elems / thread
        const float4* p = (const float4*)x;
        float4 a = p[i * 2], b = p[i * 2 + 1];
        int lo = pk_fp8_lo(a.x, a.y, 0); lo = pk_fp8_hi(a.z, a.w, lo);
        int hi = pk_fp8_lo(b.x, b.y, 0); hi = pk_fp8_hi(b.z, b.w, hi);
        ((int2*)xf8)[i] = make_int2(lo, hi);
        float s2 = a.x*a.x + a.y*a.y + a.z*a.z + a.w*a.w
                 + b.x*b.x + b.y*b.y + b.z*b.z + b.w*b.w;
        float s1 = a.x + a.y + a.z + a.w + b.x + b.y + b.z + b.w;
        #pragma unroll
        for (int off = 1; off < 64; off <<= 1) {
            s2 += __shfl_xor(s2, off);
            s1 += __shfl_xor(s1, off);
        }
        if (lane == 0) { red[wid] = s2; red[4 + wid] = s1; }
        __syncthreads();
        if (tid == 0)
            rrow[bid * 2] = (red[0] + red[1])
                + 2.f * EPS * (red[4] + red[5]) + (float)Dn * EPS * EPS;
        if (tid == 128)
            rrow[bid * 2 + 1] = (red[2] + red[3])
                + 2.f * EPS * (red[6] + red[7]) + (float)Dn * EPS * EPS;
    } else {
        const int tb = bid - 2048;
        const int kb = tb & 63, db = tb >> 6;        // 64 k-blocks x 16 d-blocks
        const int k0 = kb * 64, d0 = db * 64;
        const int tx = tid & 63, ty = tid >> 6;
        #pragma unroll
        for (int i = 0; i < 16; ++i) {
            int d = i * 4 + ty;
            t[d][tx] = w[(size_t)(d0 + d) * Kn + k0 + tx];   // 256 B coalesced
        }
        __syncthreads();
        #pragma unroll
        for (int i = 0; i < 16; ++i) {
            int kr = i * 4 + ty;
            float v = t[tx][kr];                     // stride 65: conflict-free
            wtf[(size_t)(k0 + kr) * Dn + d0 + tx] = v;
            wf8[(size_t)(k0 + kr) * Dn + d0 + tx] =
                (unsigned char)(pk_fp8_lo(v, v, 0) & 0xFF);
        }
        // column-stat partial over this block's 64 d: sum (w^2 - 2 eps w)
        float cs = 0.f;
        #pragma unroll
        for (int j = 0; j < 16; ++j) {
            float v = t[ty * 16 + j][tx];
            cs = fmaf(v, v - 2.f * EPS, cs);
        }
        cp[ty][tx] = cs;
        __syncthreads();
        if (ty == 0)
            cpart[(size_t)db * Kn + k0 + tx] = cp[0][tx] + cp[1][tx] + cp[2][tx] + cp[3][tx];
    }
}

// ---- fp8 MFMA screen GEMM: BK=128, padded q-major LDS, top-2/64-col group -
// LDS layout: row stride 144 B (pad kills conflicts); within row the d index
// d = kk*32 + q*8 + j is stored at column q*32 + kk*8 + j so one lane's four
// k-slices are contiguous 32 B (2x ds_read_b128 per fragment set).
__global__ __launch_bounds__(256, 3) void som_gemm_fp8(
    const unsigned char* __restrict__ xf8, const unsigned char* __restrict__ wf8,
    const float* __restrict__ cpart, float* __restrict__ pval) {
    __shared__ __align__(16) unsigned char As[128 * 144];
    __shared__ __align__(16) unsigned char Bs[128 * 144];
    const int tid = threadIdx.x;
    const int lane = tid & 63;
    const int wid = tid >> 6;
    const int wm = wid >> 1, wn = wid & 1;    // 2x2 waves of 64x64
    const int f = blockIdx.x;
    const int xcd = f & 7;
    const int ib = f >> 3;
    const int rb = xcd * 4 + (ib & 3);
    const int cb = ib >> 2;
    const int rowBase = rb * 128, colBase = cb * 128;

    // granule (r, s): 16 B of global row r at byte s*16; covers kk=s>>1,
    // q = 2*(s&1)+{0,1}. LDS dst: off_a (first 8B), off_a+32 (second 8B).
    int offA[4];
    const unsigned char* gsrcA[4];
    const unsigned char* gsrcB[4];
    #pragma unroll
    for (int i = 0; i < 4; ++i) {
        int g = i * 256 + tid;
        int r = g >> 3, s = g & 7;
        offA[i] = r * 144 + (2 * (s & 1)) * 32 + (s >> 1) * 8;
        gsrcA[i] = xf8 + (size_t)(rowBase + r) * Dn + s * 16;
        gsrcB[i] = wf8 + (size_t)(colBase + r) * Dn + s * 16;
    }

    f32x4 acc[4][4] = {};
    ll2 ra[4], rbv[4];
    #pragma unroll
    for (int i = 0; i < 4; ++i) {            // prefetch iter 0
        ra[i]  = *(const ll2*)(gsrcA[i]);
        rbv[i] = *(const ll2*)(gsrcB[i]);
    }

    const int mrA = (wm * 64 + (lane & 15)) * 144;
    const int nrB = (wn * 64 + (lane & 15)) * 144;
    const int qoff = (lane >> 4) * 32;

    for (int it = 0; it < 8; ++it) {
        #pragma unroll
        for (int i = 0; i < 4; ++i) {
            *(long long*)&As[offA[i]]      = ra[i][0];
            *(long long*)&As[offA[i] + 32] = ra[i][1];
            *(long long*)&Bs[offA[i]]      = rbv[i][0];
            *(long long*)&Bs[offA[i] + 32] = rbv[i][1];
        }
        __syncthreads();
        if (it < 7) {                         // prefetch next iter's globals
            int d0 = (it + 1) * 128;
            #pragma unroll
            for (int i = 0; i < 4; ++i) {
                ra[i]  = *(const ll2*)(gsrcA[i] + d0);
                rbv[i] = *(const ll2*)(gsrcB[i] + d0);
            }
        }
        #pragma unroll
        for (int kk2 = 0; kk2 < 2; ++kk2) {
            ll2 a2[4], b2[4];
            #pragma unroll
            for (int i = 0; i < 4; ++i) {
                a2[i] = *(const ll2*)&As[mrA + i * 16 * 144 + qoff + kk2 * 16];
                b2[i] = *(const ll2*)&Bs[nrB + i * 16 * 144 + qoff + kk2 * 16];
            }
            #pragma unroll
            for (int i = 0; i < 4; ++i)
                #pragma unroll
                for (int j = 0; j < 4; ++j) {
                    acc[i][j] = __builtin_amdgcn_mfma_f32_16x16x32_fp8_fp8(
                        a2[i][0], b2[j][0], acc[i][j], 0, 0, 0);
                    acc[i][j] = __builtin_amdgcn_mfma_f32_16x16x32_fp8_fp8(
                        a2[i][1], b2[j][1], acc[i][j], 0, 0, 0);
                }
        }
        __syncthreads();
    }

    // epilogue: c[k] from cpart, then packed top-2 per (row, 64-col group)
    const int cn = lane & 15, q = lane >> 4;
    const int nbase = colBase + wn * 64;
    float cv[4];
    #pragma unroll
    for (int j = 0; j < 4; ++j) {
        float s = 0.f;
        #pragma unroll
        for (int db = 0; db < 16; ++db)
            s += cpart[(size_t)db * Kn + nbase + j * 16 + cn];
        cv[j] = s;
    }
    #pragma unroll
    for (int i = 0; i < 4; ++i) {
        #pragma unroll
        for (int rg = 0; rg < 4; ++rg) {
            float p1 = 3.4e38f, p2 = 3.4e38f;
            #pragma unroll
            for (int j = 0; j < 4; ++j) {
                float p = packcand(fmaf(-2.f, acc[i][j][rg], cv[j]),
                                   nbase + j * 16 + cn);
                float lo = fminf(p1, p), hi = fmaxf(p1, p);
                p1 = lo; p2 = fminf(p2, hi);
            }
            #pragma unroll
            for (int off = 1; off < 16; off <<= 1) {
                float o1 = __shfl_xor(p1, off);
                float o2 = __shfl_xor(p2, off);
                float lo = fminf(p1, o1), hi = fmaxf(p1, o1);
                p1 = lo; p2 = fminf(hi, fminf(p2, o2));
            }
            if (cn == 0) {
                int mrow = rowBase + wm * 64 + i * 16 + q * 4 + rg;
                size_t e = (size_t)mrow * 128 + cb * 4 + wn * 2;
                pval[e] = p1; pval[e + 1] = p2;
            }
        }
    }
}

// ---- finalize: per row, exact fp32 rescore of all candidates in margin ----
__global__ __launch_bounds__(256) void som_finalize(
    const float* __restrict__ x, const float* __restrict__ wtf,
    const float* __restrict__ cpart, const float* __restrict__ loc,
    const float* __restrict__ pval, const float* __restrict__ rrow,
    float* __restrict__ dist, float* __restrict__ out) {
    const int lane = threadIdx.x & 63;
    const int row = blockIdx.x * 4 + (threadIdx.x >> 6);

    const float4* xr = (const float4*)(x + (size_t)row * Dn);
    float4 xv[4];
    #pragma unroll
    for (int j = 0; j < 4; ++j) xv[j] = xr[lane * 4 + j];
    const float rrv = rrow[row];

    float v0 = pval[(size_t)row * 128 + lane];
    float v1 = pval[(size_t)row * 128 + 64 + lane];
    float g = fminf(v0, v1);
    #pragma unroll
    for (int off = 1; off < 64; off <<= 1) g = fminf(g, __shfl_xor(g, off));
    const float thr = g + 30.0f;  // fp8 screen noise (sigma~2.7) + pack error
    unsigned long long m0 = __ballot(v0 <= thr);
    unsigned long long m1 = __ballot(v1 <= thr);

    float bestd2 = 3.4e38f; int bestk = 0x7fffffff;
    #pragma unroll
    for (int slot = 0; slot < 2; ++slot) {
        unsigned long long m = slot ? m1 : m0;
        float vs = slot ? v1 : v0;
        while (m) {
            int src = __builtin_ctzll(m); m &= m - 1;
            int k = ((int)__float_as_uint(__shfl(vs, src))) & 0xFFF;
            const float4* wr = (const float4*)(wtf + (size_t)k * Dn);
            float dt = 0.f;
            #pragma unroll
            for (int j = 0; j < 4; ++j) {
                float4 wv = wr[lane * 4 + j];
                dt += xv[j].x * wv.x + xv[j].y * wv.y + xv[j].z * wv.z + xv[j].w * wv.w;
            }
            #pragma unroll
            for (int off = 1; off < 64; off <<= 1) dt += __shfl_xor(dt, off);
            float ck = 0.f;
            #pragma unroll
            for (int db = 0; db < 16; ++db) ck += cpart[(size_t)db * Kn + k];
            float d2 = rrv + ck - 2.f * dt;
            if (d2 < bestd2 || (d2 == bestd2 && k < bestk)) { bestd2 = d2; bestk = k; }
        }
    }
    if (lane == 0) {
        out[2 * row]     = loc[2 * bestk];
        out[2 * row + 1] = loc[2 * bestk + 1];
        out[8193 + row]  = (float)bestk;
        dist[row]        = sqrtf(fmaxf(bestd2, 0.f));
    }
}

// ---- loss: single block reduces the 4096 per-row distances ----------------
__global__ __launch_bounds__(256) void som_loss(const float* __restrict__ dist,
                                                float* __restrict__ out) {
    __shared__ float red[4];
    const int tid = threadIdx.x;
    const int lane = tid & 63, wid = tid >> 6;
    const float4* p = (const float4*)dist;
    float s = 0.f;
    #pragma unroll
    for (int j = 0; j < 4; ++j) {
        float4 v = p[tid + j * 256];
        s += v.x + v.y + v.z + v.w;
    }
    #pragma unroll
    for (int off = 1; off < 64; off <<= 1) s += __shfl_xor(s, off);
    if (lane == 0) red[wid] = s;
    __syncthreads();
    if (tid == 0)
        out[8192] = (red[0] + red[1] + red[2] + red[3]) * (1.0f / (float)Bn);
}

extern "C" void kernel_launch(void* const* d_in, const int* in_sizes, int n_in,
                              void* d_out, int out_size, void* d_ws, size_t ws_size,
                              hipStream_t stream) {
    const float* x   = (const float*)d_in[0];   // [B, D]
    const float* w   = (const float*)d_in[1];   // [D, K]
    const float* loc = (const float*)d_in[2];   // [K, 2]
    float* out = (float*)d_out;

    float* rrow = (float*)d_ws;                            // 16 KB  [B]
    float* wtf  = rrow + Bn;                               // 16 MB  [K][D] fp32
    unsigned char* wf8 = (unsigned char*)(wtf + (size_t)Kn * Dn);  // 4 MB
    unsigned char* xf8 = wf8 + (size_t)Kn * Dn;            // 4 MB
    float* pval = (float*)(xf8 + (size_t)Bn * Dn);         // 2 MB packed top-2
    float* cpart = pval + (size_t)Bn * 128;                // 256 KB [16][K]
    float* dist  = cpart + 16 * Kn;                        // 16 KB  [B]

    som_prep<<<3072, 256, 0, stream>>>(x, w, xf8, rrow, wtf, wf8, cpart);
    som_gemm_fp8<<<1024, 256, 0, stream>>>(xf8, wf8, cpart, pval);
    som_finalize<<<Bn / 4, 256, 0, stream>>>(x, wtf, cpart, loc, pval, rrow, dist, out);
    som_loss<<<1, 256, 0, stream>>>(dist, out);
}